// Round 9
// baseline (20656.204 us; speedup 1.0000x reference)
//
#include <hip/hip_runtime.h>
#include <stdint.h>
#include <stddef.h>

#define CDIV(a,b) (((a)+(b)-1)/(b))

#define N_CFG  50000
#define N_AST  200000
#define N_TEST 1000
#define NNODE  (N_CFG + N_AST + N_TEST)

typedef __attribute__((ext_vector_type(8))) short bf16x8;
typedef __attribute__((ext_vector_type(4))) short s16x4;
typedef __attribute__((ext_vector_type(4))) float f32x4;

__device__ __forceinline__ unsigned short f2bf(float f) {
  union { float f; unsigned int u; } x; x.f = f;
  unsigned int r = x.u + 0x7fffu + ((x.u >> 16) & 1u);   // RNE
  return (unsigned short)(r >> 16);
}
__device__ __forceinline__ float bf2f(unsigned short b) {
  union { unsigned int u; float f; } x; x.u = ((unsigned int)b) << 16;
  return x.f;
}
__device__ __forceinline__ float bflo(unsigned int u) {
  union { unsigned int x; float f; } c; c.x = u << 16; return c.f;
}
__device__ __forceinline__ float bfhi(unsigned int u) {
  union { unsigned int x; float f; } c; c.x = u & 0xffff0000u; return c.f;
}

// ---------------------------------------------------------------- CSR build
__global__ void zero_int_kernel(int* __restrict__ p, int n) {
  int i = blockIdx.x * 256 + threadIdx.x;
  if (i < n) p[i] = 0;
}

__global__ void hist_kernel(const int* __restrict__ dst, int E, int* __restrict__ cnt) {
  int i = blockIdx.x * 256 + threadIdx.x;
  if (i < E) atomicAdd(&cnt[dst[i]], 1);
}

__global__ void copy_int_kernel(int* __restrict__ d, const int* __restrict__ s, int n) {
  int i = blockIdx.x * 256 + threadIdx.x;
  if (i < n) d[i] = s[i];
}

// single-block scan, 4 elems/thread (int4): rp[0]=0, rp[i+1]=sum cnt[0..i]
__global__ __launch_bounds__(1024) void scan_kernel(const int* __restrict__ cnt,
                                                    int* __restrict__ rp, int n) {
  __shared__ int wsum[16];
  __shared__ int carry;
  int tid = threadIdx.x;
  int lane = tid & 63, wid = tid >> 6;
  if (tid == 0) { carry = 0; rp[0] = 0; }
  __syncthreads();
  for (int base = 0; base < n; base += 4096) {
    int i0 = base + tid * 4;
    int4 v = make_int4(0, 0, 0, 0);
    if (i0 + 3 < n) {
      v = *(const int4*)(cnt + i0);
    } else if (i0 < n) {
      v.x = cnt[i0];
      if (i0 + 1 < n) v.y = cnt[i0 + 1];
      if (i0 + 2 < n) v.z = cnt[i0 + 2];
    }
    int s1 = v.x + v.y, s2 = s1 + v.z, s3 = s2 + v.w;
    int s = s3;
    #pragma unroll
    for (int o = 1; o < 64; o <<= 1) {
      int t = __shfl_up(s, o, 64);
      if (lane >= o) s += t;
    }
    if (lane == 63) wsum[wid] = s;
    __syncthreads();
    if (wid == 0) {
      int x = (lane < 16) ? wsum[lane] : 0;
      #pragma unroll
      for (int o = 1; o < 16; o <<= 1) {
        int t = __shfl_up(x, o, 64);
        if (lane >= o) x += t;
      }
      if (lane < 16) wsum[lane] = x;
    }
    __syncthreads();
    int off = carry + (wid > 0 ? wsum[wid - 1] : 0) + (s - s3);
    if (i0 < n)     rp[i0 + 1] = off + v.x;
    if (i0 + 1 < n) rp[i0 + 2] = off + s1;
    if (i0 + 2 < n) rp[i0 + 3] = off + s2;
    if (i0 + 3 < n) rp[i0 + 4] = off + s3;
    __syncthreads();
    if (tid == 0) carry += wsum[15];
    __syncthreads();
  }
}

__global__ void scatter_kernel(const int* __restrict__ src, const int* __restrict__ dst, int E,
                               int* __restrict__ cursor, int* __restrict__ outidx) {
  int i = blockIdx.x * 256 + threadIdx.x;
  if (i < E) {
    int p = atomicAdd(&cursor[dst[i]], 1);
    outidx[p] = src[i];
  }
}

// ---------------------------------------------------------------- encoders (h stored bf16)
__global__ void gather_lbl_kernel(const int* __restrict__ labels, const float* __restrict__ emb,
                                  unsigned short* __restrict__ h, int n) {
  int i = blockIdx.x * 256 + threadIdx.x;
  int node = i >> 5, l = i & 31;
  if (node < n) {
    float4 v = ((const float4*)(emb + (size_t)labels[node] * 128))[l];
    s16x4 o;
    o.x = (short)f2bf(v.x); o.y = (short)f2bf(v.y);
    o.z = (short)f2bf(v.z); o.w = (short)f2bf(v.w);
    *(s16x4*)(h + (size_t)node * 256 + l * 4) = o;
  }
}

__global__ void bcast_temb_kernel(const float* __restrict__ t, unsigned short* __restrict__ h) {
  int i = blockIdx.x * 256 + threadIdx.x;
  int node = i >> 6, l = i & 63;
  if (node < N_TEST) {
    float4 v = ((const float4*)t)[l];
    s16x4 o;
    o.x = (short)f2bf(v.x); o.y = (short)f2bf(v.y);
    o.z = (short)f2bf(v.z); o.w = (short)f2bf(v.w);
    *(s16x4*)(h + (size_t)node * 256 + l * 4) = o;
  }
}

// enc W fp32 [300][128] -> bf16 [128 n][320 k] zero-padded
__global__ void wtenc_kernel(const float* __restrict__ W, unsigned short* __restrict__ Wt) {
  int i = blockIdx.x * 256 + threadIdx.x;
  if (i >= 128 * 320) return;
  int k = i % 320, n = i / 320;
  Wt[i] = (k < 300) ? f2bf(W[(size_t)k * 128 + n]) : (unsigned short)0;
}

// content[M,300] @ W[300,128] + b -> bf16 h[row*256 + 128 + col]
__global__ __launch_bounds__(256) void enc_mfma_kernel(
    const float* __restrict__ A, int M,
    const unsigned short* __restrict__ WtE,   // [128][320] bf16
    const float* __restrict__ bias,           // [128] fp32
    unsigned short* __restrict__ h) {
  __shared__ __align__(16) unsigned short As[2][8192];
  __shared__ __align__(16) unsigned short Bs[2][8192];
  int tid = threadIdx.x, lane = tid & 63, wid = tid >> 6;
  int gm0 = blockIdx.x * 128;

  int wr = wid >> 1, wc = wid & 1;
  f32x4 acc[4][4];
  #pragma unroll
  for (int mi = 0; mi < 4; ++mi)
    #pragma unroll
    for (int ni = 0; ni < 4; ++ni) acc[mi][ni] = (f32x4){0.f, 0.f, 0.f, 0.f};

  // full 128x64 B tile = 1024 16B granules; 256 threads x 4 granules (round-8 bug:
  // tid*2 covered only rows 0..63 -> uninitialized LDS -> NaN)
  auto stageB = [&](int buf, int kt) {
    int k0 = kt * 64;
    #pragma unroll
    for (int j = 0; j < 4; ++j) {
      int q = tid * 4 + j;                 // 0..1023
      int row = q >> 3, sp = q & 7;
      int sgl = sp ^ (row & 7);
      *(uint4*)&Bs[buf][row * 64 + sp * 8] =
          *(const uint4*)(WtE + (size_t)row * 320 + k0 + sgl * 8);
    }
  };
  auto stageA = [&](int buf, int kt) {
    int k0 = kt * 64;
    #pragma unroll
    for (int j = 0; j < 4; ++j) {
      int q = tid * 4 + j;
      int row = q >> 3, s = q & 7;
      int grow = gm0 + row;
      int k = k0 + s * 8;
      float v[8];
      if (grow < M && k + 8 <= 300) {
        float4 u0 = *(const float4*)(A + (size_t)grow * 300 + k);
        float4 u1 = *(const float4*)(A + (size_t)grow * 300 + k + 4);
        v[0] = u0.x; v[1] = u0.y; v[2] = u0.z; v[3] = u0.w;
        v[4] = u1.x; v[5] = u1.y; v[6] = u1.z; v[7] = u1.w;
      } else {
        #pragma unroll
        for (int e = 0; e < 8; ++e)
          v[e] = (grow < M && k + e < 300) ? A[(size_t)grow * 300 + k + e] : 0.f;
      }
      bf16x8 o;
      #pragma unroll
      for (int e = 0; e < 8; ++e) o[e] = (short)f2bf(v[e]);
      *(bf16x8*)&As[buf][row * 64 + ((s ^ (row & 7)) * 8)] = o;
    }
  };

  const int nkt = 5;   // 320 / 64
  stageA(0, 0); stageB(0, 0);
  __syncthreads();
  for (int kt = 0; kt < nkt; ++kt) {
    int cur = kt & 1;
    if (kt + 1 < nkt) { stageA(cur ^ 1, kt + 1); stageB(cur ^ 1, kt + 1); }
    #pragma unroll
    for (int kk = 0; kk < 2; ++kk) {
      bf16x8 af[4], bfr[4];
      int slBase = kk * 4 + (lane >> 4);
      #pragma unroll
      for (int mi = 0; mi < 4; ++mi) {
        int row = wr * 64 + mi * 16 + (lane & 15);
        af[mi] = *(const bf16x8*)&As[cur][row * 64 + ((slBase ^ (row & 7)) * 8)];
      }
      #pragma unroll
      for (int ni = 0; ni < 4; ++ni) {
        int row = wc * 64 + ni * 16 + (lane & 15);
        bfr[ni] = *(const bf16x8*)&Bs[cur][row * 64 + ((slBase ^ (row & 7)) * 8)];
      }
      __builtin_amdgcn_s_setprio(1);
      #pragma unroll
      for (int mi = 0; mi < 4; ++mi)
        #pragma unroll
        for (int ni = 0; ni < 4; ++ni)
          acc[mi][ni] = __builtin_amdgcn_mfma_f32_16x16x32_bf16(bfr[ni], af[mi], acc[mi][ni], 0, 0, 0);
      __builtin_amdgcn_s_setprio(0);
    }
    __syncthreads();
  }

  // swapped layout: lane holds 4 consecutive cols for one row
  float4 b4[4];
  #pragma unroll
  for (int ni = 0; ni < 4; ++ni)
    b4[ni] = *(const float4*)(bias + wc * 64 + ni * 16 + (lane >> 4) * 4);
  #pragma unroll
  for (int mi = 0; mi < 4; ++mi) {
    int m = gm0 + wr * 64 + mi * 16 + (lane & 15);
    if (m >= M) continue;
    #pragma unroll
    for (int ni = 0; ni < 4; ++ni) {
      f32x4 v = acc[mi][ni];
      int nb = wc * 64 + ni * 16 + (lane >> 4) * 4;
      s16x4 o;
      o.x = (short)f2bf(v[0] + b4[ni].x);
      o.y = (short)f2bf(v[1] + b4[ni].y);
      o.z = (short)f2bf(v[2] + b4[ni].z);
      o.w = (short)f2bf(v[3] + b4[ni].w);
      *(s16x4*)(h + (size_t)m * 256 + 128 + nb) = o;
    }
  }
}

// ---------------------------------------------------------------- W -> bf16 transpose
// W_rel fp32 [5][6][K=256][N=256]  ->  Wt bf16 [5][6][N=256][K=256]
__global__ void wt_kernel(const float* __restrict__ W, unsigned short* __restrict__ Wt) {
  int i = blockIdx.x * 256 + threadIdx.x;
  int k = i & 255, n = (i >> 8) & 255, lr = i >> 16;
  Wt[i] = f2bf(W[((size_t)lr * 256 + k) * 256 + n]);
}

// summed bias per (layer, dst-type): bsum[l][dt][256]
__global__ void bsum_kernel(const float* __restrict__ brel, float* __restrict__ bsum) {
  int i = blockIdx.x * 256 + threadIdx.x;
  if (i >= 5 * 3 * 256) return;
  int n = i & 255, dt = (i >> 8) % 3, l = i / (3 * 256);
  float s;
  if (dt == 0)      s = brel[((size_t)l * 6 + 0) * 256 + n] + brel[((size_t)l * 6 + 2) * 256 + n] + brel[((size_t)l * 6 + 5) * 256 + n];
  else if (dt == 1) s = brel[((size_t)l * 6 + 1) * 256 + n] + brel[((size_t)l * 6 + 3) * 256 + n];
  else              s = brel[((size_t)l * 6 + 4) * 256 + n];
  bsum[i] = s;
}

// ---------------------------------------------------------------- FUSED agg + GEMM layer
// One block = 256 dst nodes x full N=256. 512 threads / 8 waves.
// Per K-step (64 cols): each thread (2 per node) gathers+sums its node's edge rows'
// 32-col slice from h (fp32 acc, L3-resident gathers) -> bf16 -> LDS A-tile; B reg-staged
// from L2-hot Wt. Eliminates the Abuf HBM round-trip (410 MB/ast layer) and all agg
// dispatches. LDS rows padded to 72 shorts (144 B): 16B-aligned b128, 2-way-free banks.
__global__ __launch_bounds__(512, 2) void fused_layer_kernel(
    const unsigned short* __restrict__ h0, const int* __restrict__ rp0, const int* __restrict__ si0,
    const unsigned short* __restrict__ h1, const int* __restrict__ rp1, const int* __restrict__ si1,
    const unsigned short* __restrict__ h2, const int* __restrict__ rp2, const int* __restrict__ si2,
    int nrel, int M,
    const unsigned short* __restrict__ Wt,   // layer base: [6][256 n][256 k] bf16
    int r0, int r1, int r2,
    const float* __restrict__ bsum,          // [256] summed bias
    const unsigned short* __restrict__ residual, unsigned short* __restrict__ out) {
  __shared__ __align__(16) unsigned short AsL[2][256 * 72];
  __shared__ __align__(16) unsigned short BsL[2][256 * 72];
  int tid = threadIdx.x, lane = tid & 63, wid = tid >> 6;
  int gm0 = blockIdx.x * 256;
  int lrow = tid >> 1;                 // node within block / B row
  int node = gm0 + lrow;
  int ch = (tid & 1) * 32;             // shorts offset within 64-col slice
  bool valid = node < M;

  int b0 = 0, e0 = 0, b1 = 0, e1 = 0, b2 = 0, e2 = 0;
  if (valid) {
    b0 = rp0[node]; e0 = rp0[node + 1];
    if (nrel > 1) { b1 = rp1[node]; e1 = rp1[node + 1]; }
    if (nrel > 2) { b2 = rp2[node]; e2 = rp2[node + 1]; }
  }

  int wr = wid >> 1, wc = wid & 1;     // 4 (M) x 2 (N) waves
  f32x4 acc[4][8];
  #pragma unroll
  for (int mi = 0; mi < 4; ++mi)
    #pragma unroll
    for (int ni = 0; ni < 8; ++ni) acc[mi][ni] = (f32x4){0.f, 0.f, 0.f, 0.f};

  int nkt = nrel * 4;

  f32x4 g0, g1, g2, g3, g4, g5, g6, g7;   // 32 fp32 gather accumulators

  auto gather = [&](int kt) {
    g0 = g1 = g2 = g3 = g4 = g5 = g6 = g7 = (f32x4){0.f, 0.f, 0.f, 0.f};
    const unsigned short* hh; const int* ss; int bb, ee;
    int rr = kt >> 2;
    if (rr == 0)      { hh = h0; ss = si0; bb = b0; ee = e0; }
    else if (rr == 1) { hh = h1; ss = si1; bb = b1; ee = e1; }
    else              { hh = h2; ss = si2; bb = b2; ee = e2; }
    int scol = (kt & 3) * 64 + ch;
    #define ACC2(ga, gb, u) \
      ga[0] += bflo(u.x); ga[1] += bfhi(u.x); ga[2] += bflo(u.y); ga[3] += bfhi(u.y); \
      gb[0] += bflo(u.z); gb[1] += bfhi(u.z); gb[2] += bflo(u.w); gb[3] += bfhi(u.w);
    int i = bb;
    for (; i + 1 < ee; i += 2) {                         // 2-edge unroll: 2x MLP
      const uint4* p0 = (const uint4*)(hh + (size_t)ss[i] * 256 + scol);
      const uint4* p1 = (const uint4*)(hh + (size_t)ss[i + 1] * 256 + scol);
      uint4 a0 = p0[0], a1 = p0[1], a2 = p0[2], a3 = p0[3];
      uint4 c0 = p1[0], c1 = p1[1], c2 = p1[2], c3 = p1[3];
      ACC2(g0, g1, a0); ACC2(g2, g3, a1); ACC2(g4, g5, a2); ACC2(g6, g7, a3);
      ACC2(g0, g1, c0); ACC2(g2, g3, c1); ACC2(g4, g5, c2); ACC2(g6, g7, c3);
    }
    if (i < ee) {
      const uint4* p0 = (const uint4*)(hh + (size_t)ss[i] * 256 + scol);
      uint4 a0 = p0[0], a1 = p0[1], a2 = p0[2], a3 = p0[3];
      ACC2(g0, g1, a0); ACC2(g2, g3, a1); ACC2(g4, g5, a2); ACC2(g6, g7, a3);
    }
    #undef ACC2
  };

  auto writeA = [&](int buf) {
    unsigned short* d = &AsL[buf][lrow * 72 + ch];
    bf16x8 o0, o1, o2, o3;
    o0[0] = (short)f2bf(g0[0]); o0[1] = (short)f2bf(g0[1]); o0[2] = (short)f2bf(g0[2]); o0[3] = (short)f2bf(g0[3]);
    o0[4] = (short)f2bf(g1[0]); o0[5] = (short)f2bf(g1[1]); o0[6] = (short)f2bf(g1[2]); o0[7] = (short)f2bf(g1[3]);
    o1[0] = (short)f2bf(g2[0]); o1[1] = (short)f2bf(g2[1]); o1[2] = (short)f2bf(g2[2]); o1[3] = (short)f2bf(g2[3]);
    o1[4] = (short)f2bf(g3[0]); o1[5] = (short)f2bf(g3[1]); o1[6] = (short)f2bf(g3[2]); o1[7] = (short)f2bf(g3[3]);
    o2[0] = (short)f2bf(g4[0]); o2[1] = (short)f2bf(g4[1]); o2[2] = (short)f2bf(g4[2]); o2[3] = (short)f2bf(g4[3]);
    o2[4] = (short)f2bf(g5[0]); o2[5] = (short)f2bf(g5[1]); o2[6] = (short)f2bf(g5[2]); o2[7] = (short)f2bf(g5[3]);
    o3[0] = (short)f2bf(g6[0]); o3[1] = (short)f2bf(g6[1]); o3[2] = (short)f2bf(g6[2]); o3[3] = (short)f2bf(g6[3]);
    o3[4] = (short)f2bf(g7[0]); o3[5] = (short)f2bf(g7[1]); o3[6] = (short)f2bf(g7[2]); o3[7] = (short)f2bf(g7[3]);
    *(bf16x8*)(d)      = o0;
    *(bf16x8*)(d + 8)  = o1;
    *(bf16x8*)(d + 16) = o2;
    *(bf16x8*)(d + 24) = o3;
  };

  auto stageB = [&](int buf, int kt) {
    int rr = kt >> 2;
    int rel = (rr == 0) ? r0 : ((rr == 1) ? r1 : r2);
    const uint4* src = (const uint4*)(Wt + ((size_t)rel * 256 + lrow) * 256 + (kt & 3) * 64 + ch);
    uint4 v0 = src[0], v1 = src[1], v2 = src[2], v3 = src[3];
    uint4* d = (uint4*)&BsL[buf][lrow * 72 + ch];
    d[0] = v0; d[1] = v1; d[2] = v2; d[3] = v3;
  };

  // prologue: build tile 0 in buf 0
  gather(0);
  writeA(0);
  stageB(0, 0);
  __syncthreads();

  int cb = 0;
  for (int kt = 0; kt < nkt; ++kt) {
    bool more = (kt + 1 < nkt);
    if (more) gather(kt + 1);            // T14: gathers issue before MFMA phase
    #pragma unroll
    for (int kk = 0; kk < 2; ++kk) {
      bf16x8 af[4], bfr[8];
      int slBase = kk * 4 + (lane >> 4);
      #pragma unroll
      for (int mi = 0; mi < 4; ++mi) {
        int row = wr * 64 + mi * 16 + (lane & 15);
        af[mi] = *(const bf16x8*)&AsL[cb][row * 72 + slBase * 8];
      }
      #pragma unroll
      for (int ni = 0; ni < 8; ++ni) {
        int row = wc * 128 + ni * 16 + (lane & 15);
        bfr[ni] = *(const bf16x8*)&BsL[cb][row * 72 + slBase * 8];
      }
      __builtin_amdgcn_s_setprio(1);
      #pragma unroll
      for (int mi = 0; mi < 4; ++mi)
        #pragma unroll
        for (int ni = 0; ni < 8; ++ni)
          acc[mi][ni] = __builtin_amdgcn_mfma_f32_16x16x32_bf16(bfr[ni], af[mi], acc[mi][ni], 0, 0, 0);
      __builtin_amdgcn_s_setprio(0);
    }
    __syncthreads();                     // all waves done reading cb
    if (more) {
      writeA(cb ^ 1);                    // cb^1's readers finished last iteration
      stageB(cb ^ 1, kt + 1);
    }
    __syncthreads();                     // next tile visible
    cb ^= 1;
  }

  // epilogue (swapped layout: lane holds 4 consecutive cols of one row)
  float4 b4[8];
  #pragma unroll
  for (int ni = 0; ni < 8; ++ni)
    b4[ni] = *(const float4*)(bsum + wc * 128 + ni * 16 + (lane >> 4) * 4);
  #pragma unroll
  for (int mi = 0; mi < 4; ++mi) {
    int m = gm0 + wr * 64 + mi * 16 + (lane & 15);
    if (m >= M) continue;
    #pragma unroll
    for (int ni = 0; ni < 8; ++ni) {
      f32x4 v = acc[mi][ni];
      int nb = wc * 128 + ni * 16 + (lane >> 4) * 4;
      float x0 = fmaxf(v[0] + b4[ni].x, 0.f);
      float x1 = fmaxf(v[1] + b4[ni].y, 0.f);
      float x2 = fmaxf(v[2] + b4[ni].z, 0.f);
      float x3 = fmaxf(v[3] + b4[ni].w, 0.f);
      if (residual) {
        s16x4 rv = *(const s16x4*)(residual + (size_t)m * 256 + nb);
        x0 += bf2f((unsigned short)rv.x); x1 += bf2f((unsigned short)rv.y);
        x2 += bf2f((unsigned short)rv.z); x3 += bf2f((unsigned short)rv.w);
      }
      s16x4 o;
      o.x = (short)f2bf(x0); o.y = (short)f2bf(x1);
      o.z = (short)f2bf(x2); o.w = (short)f2bf(x3);
      *(s16x4*)(out + (size_t)m * 256 + nb) = o;
    }
  }
}

// ---------------------------------------------------------------- decoders (bf16 h in, fp32 out)
__global__ void decode2_kernel(const unsigned short* __restrict__ h, const float* __restrict__ W,
                               const float* __restrict__ b, float* __restrict__ logits,
                               float* __restrict__ soft, int n) {
  int w = (blockIdx.x * blockDim.x + threadIdx.x) >> 6;
  int lane = threadIdx.x & 63;
  if (w >= n) return;
  s16x4 hv = *(const s16x4*)(h + (size_t)w * 256 + lane * 4);
  float x0 = bf2f((unsigned short)hv.x), x1 = bf2f((unsigned short)hv.y);
  float x2 = bf2f((unsigned short)hv.z), x3 = bf2f((unsigned short)hv.w);
  int k = lane * 4;
  float l0 = x0 * W[(k + 0) * 2 + 0] + x1 * W[(k + 1) * 2 + 0] +
             x2 * W[(k + 2) * 2 + 0] + x3 * W[(k + 3) * 2 + 0];
  float l1 = x0 * W[(k + 0) * 2 + 1] + x1 * W[(k + 1) * 2 + 1] +
             x2 * W[(k + 2) * 2 + 1] + x3 * W[(k + 3) * 2 + 1];
  #pragma unroll
  for (int m = 1; m < 64; m <<= 1) {
    l0 += __shfl_xor(l0, m, 64);
    l1 += __shfl_xor(l1, m, 64);
  }
  if (lane == 0) {
    l0 += b[0]; l1 += b[1];
    float mx = fmaxf(l0, l1);
    float e0 = expf(l0 - mx), e1 = expf(l1 - mx);
    float s = e0 + e1;
    logits[(size_t)w * 2 + 0] = l0;
    logits[(size_t)w * 2 + 1] = l1;
    soft[(size_t)w * 2 + 0] = e0 / s;
    soft[(size_t)w * 2 + 1] = e1 / s;
  }
}

__global__ void decode3_kernel(const unsigned short* __restrict__ h, const float* __restrict__ W,
                               const float* __restrict__ b, float* __restrict__ logits,
                               float* __restrict__ soft, int n) {
  int w = (blockIdx.x * blockDim.x + threadIdx.x) >> 6;
  int lane = threadIdx.x & 63;
  if (w >= n) return;
  s16x4 hv = *(const s16x4*)(h + (size_t)w * 256 + lane * 4);
  float x0 = bf2f((unsigned short)hv.x), x1 = bf2f((unsigned short)hv.y);
  float x2 = bf2f((unsigned short)hv.z), x3 = bf2f((unsigned short)hv.w);
  int k = lane * 4;
  float l0 = x0 * W[(k + 0) * 3 + 0] + x1 * W[(k + 1) * 3 + 0] +
             x2 * W[(k + 2) * 3 + 0] + x3 * W[(k + 3) * 3 + 0];
  float l1 = x0 * W[(k + 0) * 3 + 1] + x1 * W[(k + 1) * 3 + 1] +
             x2 * W[(k + 2) * 3 + 1] + x3 * W[(k + 3) * 3 + 1];
  float l2 = x0 * W[(k + 0) * 3 + 2] + x1 * W[(k + 1) * 3 + 2] +
             x2 * W[(k + 2) * 3 + 2] + x3 * W[(k + 3) * 3 + 2];
  #pragma unroll
  for (int m = 1; m < 64; m <<= 1) {
    l0 += __shfl_xor(l0, m, 64);
    l1 += __shfl_xor(l1, m, 64);
    l2 += __shfl_xor(l2, m, 64);
  }
  if (lane == 0) {
    l0 += b[0]; l1 += b[1]; l2 += b[2];
    float mx = fmaxf(fmaxf(l0, l1), l2);
    float e0 = expf(l0 - mx), e1 = expf(l1 - mx), e2 = expf(l2 - mx);
    float s = e0 + e1 + e2;
    logits[(size_t)w * 3 + 0] = l0;
    logits[(size_t)w * 3 + 1] = l1;
    logits[(size_t)w * 3 + 2] = l2;
    soft[(size_t)w * 3 + 0] = e0 / s;
    soft[(size_t)w * 3 + 1] = e1 / s;
    soft[(size_t)w * 3 + 2] = e2 / s;
  }
}

// ---------------------------------------------------------------- host
extern "C" void kernel_launch(void* const* d_in, const int* in_sizes, int n_in,
                              void* d_out, int out_size, void* d_ws, size_t ws_size,
                              hipStream_t stream) {
  (void)in_sizes; (void)n_in; (void)out_size; (void)ws_size;
  const int*   c_labels  = (const int*)  d_in[0];
  const float* c_content = (const float*)d_in[1];
  const int*   a_labels  = (const int*)  d_in[2];
  const float* a_content = (const float*)d_in[3];
  const int*   edges[6];
  for (int r = 0; r < 6; ++r) edges[r] = (const int*)d_in[4 + r];
  const float* c_lbl_emb = (const float*)d_in[10];
  const float* c_enc_W   = (const float*)d_in[11];
  const float* c_enc_b   = (const float*)d_in[12];
  const float* a_lbl_emb = (const float*)d_in[13];
  const float* a_enc_W   = (const float*)d_in[14];
  const float* a_enc_b   = (const float*)d_in[15];
  const float* t_emb     = (const float*)d_in[16];
  const float* W_rel     = (const float*)d_in[17];
  const float* b_rel     = (const float*)d_in[18];
  const float* dec_W     = (const float*)d_in[19];
  const float* dec_b     = (const float*)d_in[20];
  const float* adec_W    = (const float*)d_in[21];
  const float* adec_b    = (const float*)d_in[22];
  float* out = (float*)d_out;

  static const int E_CNT[6]    = {200000, 400000, 200000, 200000, 50000, 50000};
  static const int REL_DSTN[6] = {N_CFG, N_AST, N_CFG, N_AST, N_TEST, N_CFG};

  char* ws = (char*)d_ws;
  size_t off = 0;
  auto alloc = [&](size_t bytes) -> void* {
    void* p = ws + off;
    off += (bytes + 255) & ~(size_t)255;
    return p;
  };
  unsigned short* buf0 = (unsigned short*)alloc((size_t)NNODE * 256 * 2);
  unsigned short* buf1 = (unsigned short*)alloc((size_t)NNODE * 256 * 2);
  unsigned short* Wt   = (unsigned short*)alloc((size_t)5 * 6 * 256 * 256 * 2);
  unsigned short* WtEc = (unsigned short*)alloc((size_t)128 * 320 * 2);
  unsigned short* WtEa = (unsigned short*)alloc((size_t)128 * 320 * 2);
  float*          bsum = (float*)alloc((size_t)5 * 3 * 256 * 4);
  int* rowptr[6];
  int* srcidx[6];
  for (int r = 0; r < 6; ++r) rowptr[r] = (int*)alloc((size_t)(REL_DSTN[r] + 1) * 4);
  for (int r = 0; r < 6; ++r) srcidx[r] = (int*)alloc((size_t)E_CNT[r] * 4);
  int* cursor = (int*)alloc((size_t)(N_AST + 1) * 4);

  // weights -> bf16; bias sums
  wt_kernel<<<CDIV(5 * 6 * 256 * 256, 256), 256, 0, stream>>>(W_rel, Wt);
  wtenc_kernel<<<CDIV(128 * 320, 256), 256, 0, stream>>>(c_enc_W, WtEc);
  wtenc_kernel<<<CDIV(128 * 320, 256), 256, 0, stream>>>(a_enc_W, WtEa);
  bsum_kernel<<<CDIV(5 * 3 * 256, 256), 256, 0, stream>>>(b_rel, bsum);

  // CSR (dst-sorted) per relation
  for (int r = 0; r < 6; ++r) {
    int nd = REL_DSTN[r], E = E_CNT[r];
    const int* esrc = edges[r];
    const int* edst = edges[r] + E;
    zero_int_kernel<<<CDIV(nd, 256), 256, 0, stream>>>(cursor, nd);
    hist_kernel<<<CDIV(E, 256), 256, 0, stream>>>(edst, E, cursor);
    scan_kernel<<<1, 1024, 0, stream>>>(cursor, rowptr[r], nd);
    copy_int_kernel<<<CDIV(nd, 256), 256, 0, stream>>>(cursor, rowptr[r], nd);
    scatter_kernel<<<CDIV(E, 256), 256, 0, stream>>>(esrc, edst, E, cursor, srcidx[r]);
  }

  const size_t OFF_CFG = 0;
  const size_t OFF_AST = (size_t)N_CFG * 256;
  const size_t OFF_TST = (size_t)(N_CFG + N_AST) * 256;

  // encoders -> buf0 (bf16)
  gather_lbl_kernel<<<CDIV(N_CFG * 32, 256), 256, 0, stream>>>(c_labels, c_lbl_emb, buf0 + OFF_CFG, N_CFG);
  gather_lbl_kernel<<<CDIV(N_AST * 32, 256), 256, 0, stream>>>(a_labels, a_lbl_emb, buf0 + OFF_AST, N_AST);
  enc_mfma_kernel<<<CDIV(N_CFG, 128), 256, 0, stream>>>(c_content, N_CFG, WtEc, c_enc_b, buf0 + OFF_CFG);
  enc_mfma_kernel<<<CDIV(N_AST, 128), 256, 0, stream>>>(a_content, N_AST, WtEa, a_enc_b, buf0 + OFF_AST);
  bcast_temb_kernel<<<CDIV(N_TEST * 64, 256), 256, 0, stream>>>(t_emb, buf0 + OFF_TST);

  unsigned short* h_in = buf0;
  unsigned short* h_out = buf1;
  for (int l = 0; l < 5; ++l) {
    bool use_res = (l == 1 || l == 3);
    const unsigned short* WtL = Wt + (size_t)l * 6 * 256 * 256;
    // dst cfg: rels 0(cc: src cfg), 2(ac: src ast), 5(tc: src test); K = 768
    fused_layer_kernel<<<CDIV(N_CFG, 256), 512, 0, stream>>>(
        h_in + OFF_CFG, rowptr[0], srcidx[0],
        h_in + OFF_AST, rowptr[2], srcidx[2],
        h_in + OFF_TST, rowptr[5], srcidx[5],
        3, N_CFG, WtL, 0, 2, 5, bsum + (size_t)(l * 3 + 0) * 256,
        use_res ? h_in + OFF_CFG : nullptr, h_out + OFF_CFG);
    // dst ast: rels 1(aa: src ast), 3(ca: src cfg); K = 512
    fused_layer_kernel<<<CDIV(N_AST, 256), 512, 0, stream>>>(
        h_in + OFF_AST, rowptr[1], srcidx[1],
        h_in + OFF_CFG, rowptr[3], srcidx[3],
        (const unsigned short*)nullptr, (const int*)nullptr, (const int*)nullptr,
        2, N_AST, WtL, 1, 3, -1, bsum + (size_t)(l * 3 + 1) * 256,
        use_res ? h_in + OFF_AST : nullptr, h_out + OFF_AST);
    // dst test: rel 4(ct: src cfg); K = 256
    fused_layer_kernel<<<CDIV(N_TEST, 256), 512, 0, stream>>>(
        h_in + OFF_CFG, rowptr[4], srcidx[4],
        (const unsigned short*)nullptr, (const int*)nullptr, (const int*)nullptr,
        (const unsigned short*)nullptr, (const int*)nullptr, (const int*)nullptr,
        1, N_TEST, WtL, 4, -1, -1, bsum + (size_t)(l * 3 + 2) * 256,
        use_res ? h_in + OFF_TST : nullptr, h_out + OFF_TST);
    unsigned short* t = h_in; h_in = h_out; h_out = t;
  }

  decode2_kernel<<<CDIV(N_CFG, 4), 256, 0, stream>>>(h_in + OFF_CFG, dec_W, dec_b,
                                                     out, out + 100000, N_CFG);
  decode3_kernel<<<CDIV(N_AST, 4), 256, 0, stream>>>(h_in + OFF_AST, adec_W, adec_b,
                                                     out + 200000, out + 800000, N_AST);
}

// Round 10
// 2758.321 us; speedup vs baseline: 7.4887x; 7.4887x over previous
//
#include <hip/hip_runtime.h>
#include <stdint.h>
#include <stddef.h>

#define CDIV(a,b) (((a)+(b)-1)/(b))

#define N_CFG  50000
#define N_AST  200000
#define N_TEST 1000
#define NNODE  (N_CFG + N_AST + N_TEST)

typedef __attribute__((ext_vector_type(8))) short bf16x8;
typedef __attribute__((ext_vector_type(4))) short s16x4;
typedef __attribute__((ext_vector_type(4))) float f32x4;

__device__ __forceinline__ unsigned short f2bf(float f) {
  union { float f; unsigned int u; } x; x.f = f;
  unsigned int r = x.u + 0x7fffu + ((x.u >> 16) & 1u);   // RNE
  return (unsigned short)(r >> 16);
}
__device__ __forceinline__ float bf2f(unsigned short b) {
  union { unsigned int u; float f; } x; x.u = ((unsigned int)b) << 16;
  return x.f;
}

__device__ __forceinline__ void gload_lds16(const void* g, void* l) {
  __builtin_amdgcn_global_load_lds((const __attribute__((address_space(1))) unsigned int*)g,
                                   (__attribute__((address_space(3))) unsigned int*)l,
                                   16, 0, 0);
}

// ---------------------------------------------------------------- CSR build
__global__ void zero_int_kernel(int* __restrict__ p, int n) {
  int i = blockIdx.x * 256 + threadIdx.x;
  if (i < n) p[i] = 0;
}

__global__ void hist_kernel(const int* __restrict__ dst, int E, int* __restrict__ cnt) {
  int i = blockIdx.x * 256 + threadIdx.x;
  if (i < E) atomicAdd(&cnt[dst[i]], 1);
}

__global__ void copy_int_kernel(int* __restrict__ d, const int* __restrict__ s, int n) {
  int i = blockIdx.x * 256 + threadIdx.x;
  if (i < n) d[i] = s[i];
}

// single-block scan, 4 elems/thread (int4): rp[0]=0, rp[i+1]=sum cnt[0..i]
__global__ __launch_bounds__(1024) void scan_kernel(const int* __restrict__ cnt,
                                                    int* __restrict__ rp, int n) {
  __shared__ int wsum[16];
  __shared__ int carry;
  int tid = threadIdx.x;
  int lane = tid & 63, wid = tid >> 6;
  if (tid == 0) { carry = 0; rp[0] = 0; }
  __syncthreads();
  for (int base = 0; base < n; base += 4096) {
    int i0 = base + tid * 4;
    int4 v = make_int4(0, 0, 0, 0);
    if (i0 + 3 < n) {
      v = *(const int4*)(cnt + i0);
    } else if (i0 < n) {
      v.x = cnt[i0];
      if (i0 + 1 < n) v.y = cnt[i0 + 1];
      if (i0 + 2 < n) v.z = cnt[i0 + 2];
    }
    int s1 = v.x + v.y, s2 = s1 + v.z, s3 = s2 + v.w;
    int s = s3;
    #pragma unroll
    for (int o = 1; o < 64; o <<= 1) {
      int t = __shfl_up(s, o, 64);
      if (lane >= o) s += t;
    }
    if (lane == 63) wsum[wid] = s;
    __syncthreads();
    if (wid == 0) {
      int x = (lane < 16) ? wsum[lane] : 0;
      #pragma unroll
      for (int o = 1; o < 16; o <<= 1) {
        int t = __shfl_up(x, o, 64);
        if (lane >= o) x += t;
      }
      if (lane < 16) wsum[lane] = x;
    }
    __syncthreads();
    int off = carry + (wid > 0 ? wsum[wid - 1] : 0) + (s - s3);
    if (i0 < n)     rp[i0 + 1] = off + v.x;
    if (i0 + 1 < n) rp[i0 + 2] = off + s1;
    if (i0 + 2 < n) rp[i0 + 3] = off + s2;
    if (i0 + 3 < n) rp[i0 + 4] = off + s3;
    __syncthreads();
    if (tid == 0) carry += wsum[15];
    __syncthreads();
  }
}

__global__ void scatter_kernel(const int* __restrict__ src, const int* __restrict__ dst, int E,
                               int* __restrict__ cursor, int* __restrict__ outidx) {
  int i = blockIdx.x * 256 + threadIdx.x;
  if (i < E) {
    int p = atomicAdd(&cursor[dst[i]], 1);
    outidx[p] = src[i];
  }
}

// ---------------------------------------------------------------- encoders (h stored bf16)
__global__ void gather_lbl_kernel(const int* __restrict__ labels, const float* __restrict__ emb,
                                  unsigned short* __restrict__ h, int n) {
  int i = blockIdx.x * 256 + threadIdx.x;
  int node = i >> 5, l = i & 31;
  if (node < n) {
    float4 v = ((const float4*)(emb + (size_t)labels[node] * 128))[l];
    s16x4 o;
    o.x = (short)f2bf(v.x); o.y = (short)f2bf(v.y);
    o.z = (short)f2bf(v.z); o.w = (short)f2bf(v.w);
    *(s16x4*)(h + (size_t)node * 256 + l * 4) = o;
  }
}

__global__ void bcast_temb_kernel(const float* __restrict__ t, unsigned short* __restrict__ h) {
  int i = blockIdx.x * 256 + threadIdx.x;
  int node = i >> 6, l = i & 63;
  if (node < N_TEST) {
    float4 v = ((const float4*)t)[l];
    s16x4 o;
    o.x = (short)f2bf(v.x); o.y = (short)f2bf(v.y);
    o.z = (short)f2bf(v.z); o.w = (short)f2bf(v.w);
    *(s16x4*)(h + (size_t)node * 256 + l * 4) = o;
  }
}

// enc W fp32 [300][128] -> bf16 [128 n][320 k] zero-padded
__global__ void wtenc_kernel(const float* __restrict__ W, unsigned short* __restrict__ Wt) {
  int i = blockIdx.x * 256 + threadIdx.x;
  if (i >= 128 * 320) return;
  int k = i % 320, n = i / 320;
  Wt[i] = (k < 300) ? f2bf(W[(size_t)k * 128 + n]) : (unsigned short)0;
}

// content[M,300] @ W[300,128] + b -> bf16 h[row*256 + 128 + col]
__global__ __launch_bounds__(256) void enc_mfma_kernel(
    const float* __restrict__ A, int M,
    const unsigned short* __restrict__ WtE,   // [128][320] bf16
    const float* __restrict__ bias,           // [128] fp32
    unsigned short* __restrict__ h) {
  __shared__ __align__(16) unsigned short As[2][8192];
  __shared__ __align__(16) unsigned short Bs[2][8192];
  int tid = threadIdx.x, lane = tid & 63, wid = tid >> 6;
  int gm0 = blockIdx.x * 128;

  int wr = wid >> 1, wc = wid & 1;
  f32x4 acc[4][4];
  #pragma unroll
  for (int mi = 0; mi < 4; ++mi)
    #pragma unroll
    for (int ni = 0; ni < 4; ++ni) acc[mi][ni] = (f32x4){0.f, 0.f, 0.f, 0.f};

  // full 128x64 B tile = 1024 16B granules; 256 threads x 4 granules
  auto stageB = [&](int buf, int kt) {
    int k0 = kt * 64;
    #pragma unroll
    for (int j = 0; j < 4; ++j) {
      int q = tid * 4 + j;                 // 0..1023
      int row = q >> 3, sp = q & 7;
      int sgl = sp ^ (row & 7);
      *(uint4*)&Bs[buf][row * 64 + sp * 8] =
          *(const uint4*)(WtE + (size_t)row * 320 + k0 + sgl * 8);
    }
  };
  auto stageA = [&](int buf, int kt) {
    int k0 = kt * 64;
    #pragma unroll
    for (int j = 0; j < 4; ++j) {
      int q = tid * 4 + j;
      int row = q >> 3, s = q & 7;
      int grow = gm0 + row;
      int k = k0 + s * 8;
      float v[8];
      if (grow < M && k + 8 <= 300) {
        float4 u0 = *(const float4*)(A + (size_t)grow * 300 + k);
        float4 u1 = *(const float4*)(A + (size_t)grow * 300 + k + 4);
        v[0] = u0.x; v[1] = u0.y; v[2] = u0.z; v[3] = u0.w;
        v[4] = u1.x; v[5] = u1.y; v[6] = u1.z; v[7] = u1.w;
      } else {
        #pragma unroll
        for (int e = 0; e < 8; ++e)
          v[e] = (grow < M && k + e < 300) ? A[(size_t)grow * 300 + k + e] : 0.f;
      }
      bf16x8 o;
      #pragma unroll
      for (int e = 0; e < 8; ++e) o[e] = (short)f2bf(v[e]);
      *(bf16x8*)&As[buf][row * 64 + ((s ^ (row & 7)) * 8)] = o;
    }
  };

  const int nkt = 5;   // 320 / 64
  stageA(0, 0); stageB(0, 0);
  __syncthreads();
  for (int kt = 0; kt < nkt; ++kt) {
    int cur = kt & 1;
    if (kt + 1 < nkt) { stageA(cur ^ 1, kt + 1); stageB(cur ^ 1, kt + 1); }
    #pragma unroll
    for (int kk = 0; kk < 2; ++kk) {
      bf16x8 af[4], bfr[4];
      int slBase = kk * 4 + (lane >> 4);
      #pragma unroll
      for (int mi = 0; mi < 4; ++mi) {
        int row = wr * 64 + mi * 16 + (lane & 15);
        af[mi] = *(const bf16x8*)&As[cur][row * 64 + ((slBase ^ (row & 7)) * 8)];
      }
      #pragma unroll
      for (int ni = 0; ni < 4; ++ni) {
        int row = wc * 64 + ni * 16 + (lane & 15);
        bfr[ni] = *(const bf16x8*)&Bs[cur][row * 64 + ((slBase ^ (row & 7)) * 8)];
      }
      __builtin_amdgcn_s_setprio(1);
      #pragma unroll
      for (int mi = 0; mi < 4; ++mi)
        #pragma unroll
        for (int ni = 0; ni < 4; ++ni)
          acc[mi][ni] = __builtin_amdgcn_mfma_f32_16x16x32_bf16(bfr[ni], af[mi], acc[mi][ni], 0, 0, 0);
      __builtin_amdgcn_s_setprio(0);
    }
    __syncthreads();
  }

  // swapped layout: lane holds 4 consecutive cols for one row
  float4 b4[4];
  #pragma unroll
  for (int ni = 0; ni < 4; ++ni)
    b4[ni] = *(const float4*)(bias + wc * 64 + ni * 16 + (lane >> 4) * 4);
  #pragma unroll
  for (int mi = 0; mi < 4; ++mi) {
    int m = gm0 + wr * 64 + mi * 16 + (lane & 15);
    if (m >= M) continue;
    #pragma unroll
    for (int ni = 0; ni < 4; ++ni) {
      f32x4 v = acc[mi][ni];
      int nb = wc * 64 + ni * 16 + (lane >> 4) * 4;
      s16x4 o;
      o.x = (short)f2bf(v[0] + b4[ni].x);
      o.y = (short)f2bf(v[1] + b4[ni].y);
      o.z = (short)f2bf(v[2] + b4[ni].z);
      o.w = (short)f2bf(v[3] + b4[ni].w);
      *(s16x4*)(h + (size_t)m * 256 + 128 + nb) = o;
    }
  }
}

// ---------------------------------------------------------------- W -> bf16 transpose
// W_rel fp32 [5][6][K=256][N=256]  ->  Wt bf16 [5][6][N=256][K=256]
__global__ void wt_kernel(const float* __restrict__ W, unsigned short* __restrict__ Wt) {
  int i = blockIdx.x * 256 + threadIdx.x;
  int k = i & 255, n = (i >> 8) & 255, lr = i >> 16;
  Wt[i] = f2bf(W[((size_t)lr * 256 + k) * 256 + n]);
}

// summed bias per (layer, dst-type): bsum[l][dt][256]
__global__ void bsum_kernel(const float* __restrict__ brel, float* __restrict__ bsum) {
  int i = blockIdx.x * 256 + threadIdx.x;
  if (i >= 5 * 3 * 256) return;
  int n = i & 255, dt = (i >> 8) % 3, l = i / (3 * 256);
  float s;
  if (dt == 0)      s = brel[((size_t)l * 6 + 0) * 256 + n] + brel[((size_t)l * 6 + 2) * 256 + n] + brel[((size_t)l * 6 + 5) * 256 + n];
  else if (dt == 1) s = brel[((size_t)l * 6 + 1) * 256 + n] + brel[((size_t)l * 6 + 3) * 256 + n];
  else              s = brel[((size_t)l * 6 + 4) * 256 + n];
  bsum[i] = s;
}

// ---------------------------------------------------------------- fused aggregation (per dst type)
// wave per dst node; 2 half-waves process 2 edges concurrently (16B/lane), shfl_xor(32) reduce.
// Output written K-step-TILED: A[mt][kt][row 256][col 64] so the GEMM stages contiguously.
__global__ void agg_fused_kernel(
    const unsigned short* __restrict__ h0, const int* __restrict__ rp0, const int* __restrict__ si0,
    const unsigned short* __restrict__ h1, const int* __restrict__ rp1, const int* __restrict__ si1,
    const unsigned short* __restrict__ h2, const int* __restrict__ rp2, const int* __restrict__ si2,
    int nrel, unsigned short* __restrict__ A, int strideK, int n) {
  int w = (blockIdx.x * blockDim.x + threadIdx.x) >> 6;
  int lane = threadIdx.x & 63;
  if (w >= n) return;
  int half = lane >> 5, l32 = lane & 31;
  int nkt = strideK >> 6;
  size_t tilebase = ((size_t)(w >> 8) * nkt * 256 + (w & 255)) * 64;   // + kt*16384
  auto do_rel = [&](const unsigned short* h, const int* rp, const int* si, int cOff) {
    int b = rp[w], e = rp[w + 1];
    float acc[8] = {0.f, 0.f, 0.f, 0.f, 0.f, 0.f, 0.f, 0.f};
    for (int i = b + half; i < e; i += 2) {
      bf16x8 v = *(const bf16x8*)(h + (size_t)si[i] * 256 + l32 * 8);
      #pragma unroll
      for (int k = 0; k < 8; ++k) acc[k] += bf2f((unsigned short)v[k]);
    }
    #pragma unroll
    for (int k = 0; k < 8; ++k) acc[k] += __shfl_xor(acc[k], 32, 64);
    if (half == 0) {
      bf16x8 o;
      #pragma unroll
      for (int k = 0; k < 8; ++k) o[k] = (short)f2bf(acc[k]);
      int kt = (cOff >> 6) + (l32 >> 3);        // which 64-col K-tile
      int cc = (l32 & 7) * 8;                   // col within tile
      *(bf16x8*)(A + tilebase + (size_t)kt * 16384 + cc) = o;
    }
  };
  do_rel(h0, rp0, si0, 0);
  if (nrel > 1) do_rel(h1, rp1, si1, 256);
  if (nrel > 2) do_rel(h2, rp2, si2, 512);
}

// ---------------------------------------------------------------- MFMA layer GEMM
// BM=256, BN=256 (full N), 512 threads / 8 waves, each wave 64M x 128N.
// A is K-step-tiled [mt][kt][256][64] (contiguous 32 KB stage). Double-buffered A+B in a
// single 135 KB LDS arena; counted-vmcnt(8) pipeline; never vmcnt(0) mid-loop.
// Epilogue: post-activation tile staged to LDS (row stride 264 shorts -> ~2-way banks),
// then COALESCED stream-out (256 B contiguous per lane) with residual fused — replaces
// the former scattered 8 B stores/loads.
__global__ __launch_bounds__(512, 2) void gemm_mfma_kernel(
    const unsigned short* __restrict__ A, int M, int K,
    const unsigned short* __restrict__ Wt,
    const float* __restrict__ bsum,          // [256] summed bias, this (layer,dsttype)
    int r0, int r1, int r2,
    const unsigned short* __restrict__ residual, unsigned short* __restrict__ out) {
  __shared__ __align__(16) unsigned short S[256 * 264];   // 135168 B arena
  unsigned short (*AsL)[16384] = (unsigned short (*)[16384])(&S[0]);       // 2 x 32 KB
  unsigned short (*BsL)[16384] = (unsigned short (*)[16384])(&S[32768]);   // 2 x 32 KB
  int tid = threadIdx.x, lane = tid & 63, wid = tid >> 6;
  int gm0 = blockIdx.x * 256;
  int rels[3] = {r0, r1, r2};

  int wr = wid >> 1, wc = wid & 1;         // 4 (M) x 2 (N) waves
  f32x4 acc[4][8];
  #pragma unroll
  for (int mi = 0; mi < 4; ++mi)
    #pragma unroll
    for (int ni = 0; ni < 8; ++ni) acc[mi][ni] = (f32x4){0.f, 0.f, 0.f, 0.f};

  int nkt = K >> 6;       // 4 / 8 / 12

  auto stageA = [&](int buf, int kt) {
    if (kt > nkt - 1) kt = nkt - 1;        // clamp: uniform vmcnt counting at tail
    const unsigned short* base = A + ((size_t)blockIdx.x * nkt + kt) * 16384;
    #pragma unroll
    for (int i = 0; i < 4; ++i) {
      int instr = wid * 4 + i;             // 0..31
      int P = instr * 64 + lane;           // 0..2047 physical 16B slot
      int row = P >> 3, sp = P & 7;
      int s = sp ^ (row & 7);
      gload_lds16(base + row * 64 + s * 8, &AsL[buf][instr * 512]);
    }
  };
  auto stageB = [&](int buf, int kt) {
    if (kt > nkt - 1) kt = nkt - 1;
    int k0 = kt * 64;
    #pragma unroll
    for (int i = 0; i < 4; ++i) {
      int instr = wid * 4 + i;
      int P = instr * 64 + lane;
      int row = P >> 3, sp = P & 7;
      int s = sp ^ (row & 7);
      gload_lds16(Wt + ((size_t)rels[k0 >> 8] * 256 + row) * 256 + (k0 & 255) + s * 8,
                  &BsL[buf][instr * 512]);
    }
  };

  // prologue: tiles 0,1 into bufs 0,1 (16 loads/wave); vmcnt(8) forces tile0
  stageA(0, 0); stageB(0, 0); stageA(1, 1); stageB(1, 1);
  asm volatile("s_waitcnt vmcnt(8)" ::: "memory");
  __builtin_amdgcn_s_barrier();

  int cb = 0;
  for (int kt = 0; kt < nkt; ++kt) {
    #pragma unroll
    for (int kk = 0; kk < 2; ++kk) {
      bf16x8 af[4], bfr[8];
      int slBase = kk * 4 + (lane >> 4);
      #pragma unroll
      for (int mi = 0; mi < 4; ++mi) {
        int row = wr * 64 + mi * 16 + (lane & 15);
        af[mi] = *(const bf16x8*)&AsL[cb][row * 64 + ((slBase ^ (row & 7)) * 8)];
      }
      #pragma unroll
      for (int ni = 0; ni < 8; ++ni) {
        int row = wc * 128 + ni * 16 + (lane & 15);
        bfr[ni] = *(const bf16x8*)&BsL[cb][row * 64 + ((slBase ^ (row & 7)) * 8)];
      }
      __builtin_amdgcn_s_setprio(1);
      #pragma unroll
      for (int mi = 0; mi < 4; ++mi)
        #pragma unroll
        for (int ni = 0; ni < 8; ++ni)
          acc[mi][ni] = __builtin_amdgcn_mfma_f32_16x16x32_bf16(bfr[ni], af[mi], acc[mi][ni], 0, 0, 0);
      __builtin_amdgcn_s_setprio(0);
    }
    if (kt + 1 < nkt) {
      __builtin_amdgcn_s_barrier();        // all waves done reading buffer cb
      stageB(cb, kt + 2);                  // overwrite cb with tile kt+2
      stageA(cb, kt + 2);
      asm volatile("s_waitcnt vmcnt(8)" ::: "memory");   // tile kt+1's loads landed
      __builtin_amdgcn_s_barrier();
      cb ^= 1;
    }
  }
  asm volatile("s_waitcnt vmcnt(0)" ::: "memory");       // drain clamped tail loads
  __builtin_amdgcn_sched_barrier(0);
  __builtin_amdgcn_s_barrier();            // all waves done with A/B LDS before reuse

  // ---- epilogue phase 1: bias+relu, stage bf16 tile to LDS (swapped layout: lane
  // holds 4 consecutive cols of one row; 8B LDS stores, stride-264 rows ~2-way banks)
  float4 b4[8];
  #pragma unroll
  for (int ni = 0; ni < 8; ++ni)
    b4[ni] = *(const float4*)(bsum + wc * 128 + ni * 16 + (lane >> 4) * 4);
  #pragma unroll
  for (int mi = 0; mi < 4; ++mi) {
    int lr = wr * 64 + mi * 16 + (lane & 15);
    #pragma unroll
    for (int ni = 0; ni < 8; ++ni) {
      f32x4 v = acc[mi][ni];
      int nb = wc * 128 + ni * 16 + (lane >> 4) * 4;
      s16x4 o;
      o.x = (short)f2bf(fmaxf(v[0] + b4[ni].x, 0.f));
      o.y = (short)f2bf(fmaxf(v[1] + b4[ni].y, 0.f));
      o.z = (short)f2bf(fmaxf(v[2] + b4[ni].z, 0.f));
      o.w = (short)f2bf(fmaxf(v[3] + b4[ni].w, 0.f));
      *(s16x4*)&S[lr * 264 + nb] = o;
    }
  }
  __builtin_amdgcn_s_barrier();

  // ---- epilogue phase 2: coalesced stream-out with fused residual.
  // thread t -> row t>>1, cols [(t&1)*128, +128): 256 B contiguous per lane.
  {
    int row = tid >> 1, cb0 = (tid & 1) * 128;
    int m = gm0 + row;
    if (m < M) {
      const unsigned short* ls = &S[row * 264 + cb0];
      unsigned short* gp = out + (size_t)m * 256 + cb0;
      if (residual) {
        const unsigned short* rp = residual + (size_t)m * 256 + cb0;
        #pragma unroll
        for (int j = 0; j < 16; ++j) {
          bf16x8 v = *(const bf16x8*)(ls + j * 8);
          bf16x8 r = *(const bf16x8*)(rp + j * 8);
          bf16x8 o;
          #pragma unroll
          for (int e = 0; e < 8; ++e)
            o[e] = (short)f2bf(bf2f((unsigned short)v[e]) + bf2f((unsigned short)r[e]));
          *(bf16x8*)(gp + j * 8) = o;
        }
      } else {
        #pragma unroll
        for (int j = 0; j < 16; ++j)
          *(bf16x8*)(gp + j * 8) = *(const bf16x8*)(ls + j * 8);
      }
    }
  }
}

// ---------------------------------------------------------------- decoders (bf16 h in, fp32 out)
__global__ void decode2_kernel(const unsigned short* __restrict__ h, const float* __restrict__ W,
                               const float* __restrict__ b, float* __restrict__ logits,
                               float* __restrict__ soft, int n) {
  int w = (blockIdx.x * blockDim.x + threadIdx.x) >> 6;
  int lane = threadIdx.x & 63;
  if (w >= n) return;
  s16x4 hv = *(const s16x4*)(h + (size_t)w * 256 + lane * 4);
  float x0 = bf2f((unsigned short)hv.x), x1 = bf2f((unsigned short)hv.y);
  float x2 = bf2f((unsigned short)hv.z), x3 = bf2f((unsigned short)hv.w);
  int k = lane * 4;
  float l0 = x0 * W[(k + 0) * 2 + 0] + x1 * W[(k + 1) * 2 + 0] +
             x2 * W[(k + 2) * 2 + 0] + x3 * W[(k + 3) * 2 + 0];
  float l1 = x0 * W[(k + 0) * 2 + 1] + x1 * W[(k + 1) * 2 + 1] +
             x2 * W[(k + 2) * 2 + 1] + x3 * W[(k + 3) * 2 + 1];
  #pragma unroll
  for (int m = 1; m < 64; m <<= 1) {
    l0 += __shfl_xor(l0, m, 64);
    l1 += __shfl_xor(l1, m, 64);
  }
  if (lane == 0) {
    l0 += b[0]; l1 += b[1];
    float mx = fmaxf(l0, l1);
    float e0 = expf(l0 - mx), e1 = expf(l1 - mx);
    float s = e0 + e1;
    logits[(size_t)w * 2 + 0] = l0;
    logits[(size_t)w * 2 + 1] = l1;
    soft[(size_t)w * 2 + 0] = e0 / s;
    soft[(size_t)w * 2 + 1] = e1 / s;
  }
}

__global__ void decode3_kernel(const unsigned short* __restrict__ h, const float* __restrict__ W,
                               const float* __restrict__ b, float* __restrict__ logits,
                               float* __restrict__ soft, int n) {
  int w = (blockIdx.x * blockDim.x + threadIdx.x) >> 6;
  int lane = threadIdx.x & 63;
  if (w >= n) return;
  s16x4 hv = *(const s16x4*)(h + (size_t)w * 256 + lane * 4);
  float x0 = bf2f((unsigned short)hv.x), x1 = bf2f((unsigned short)hv.y);
  float x2 = bf2f((unsigned short)hv.z), x3 = bf2f((unsigned short)hv.w);
  int k = lane * 4;
  float l0 = x0 * W[(k + 0) * 3 + 0] + x1 * W[(k + 1) * 3 + 0] +
             x2 * W[(k + 2) * 3 + 0] + x3 * W[(k + 3) * 3 + 0];
  float l1 = x0 * W[(k + 0) * 3 + 1] + x1 * W[(k + 1) * 3 + 1] +
             x2 * W[(k + 2) * 3 + 1] + x3 * W[(k + 3) * 3 + 1];
  float l2 = x0 * W[(k + 0) * 3 + 2] + x1 * W[(k + 1) * 3 + 2] +
             x2 * W[(k + 2) * 3 + 2] + x3 * W[(k + 3) * 3 + 2];
  #pragma unroll
  for (int m = 1; m < 64; m <<= 1) {
    l0 += __shfl_xor(l0, m, 64);
    l1 += __shfl_xor(l1, m, 64);
    l2 += __shfl_xor(l2, m, 64);
  }
  if (lane == 0) {
    l0 += b[0]; l1 += b[1]; l2 += b[2];
    float mx = fmaxf(fmaxf(l0, l1), l2);
    float e0 = expf(l0 - mx), e1 = expf(l1 - mx), e2 = expf(l2 - mx);
    float s = e0 + e1 + e2;
    logits[(size_t)w * 3 + 0] = l0;
    logits[(size_t)w * 3 + 1] = l1;
    logits[(size_t)w * 3 + 2] = l2;
    soft[(size_t)w * 3 + 0] = e0 / s;
    soft[(size_t)w * 3 + 1] = e1 / s;
    soft[(size_t)w * 3 + 2] = e2 / s;
  }
}

// ---------------------------------------------------------------- host
extern "C" void kernel_launch(void* const* d_in, const int* in_sizes, int n_in,
                              void* d_out, int out_size, void* d_ws, size_t ws_size,
                              hipStream_t stream) {
  (void)in_sizes; (void)n_in; (void)out_size; (void)ws_size;
  const int*   c_labels  = (const int*)  d_in[0];
  const float* c_content = (const float*)d_in[1];
  const int*   a_labels  = (const int*)  d_in[2];
  const float* a_content = (const float*)d_in[3];
  const int*   edges[6];
  for (int r = 0; r < 6; ++r) edges[r] = (const int*)d_in[4 + r];
  const float* c_lbl_emb = (const float*)d_in[10];
  const float* c_enc_W   = (const float*)d_in[11];
  const float* c_enc_b   = (const float*)d_in[12];
  const float* a_lbl_emb = (const float*)d_in[13];
  const float* a_enc_W   = (const float*)d_in[14];
  const float* a_enc_b   = (const float*)d_in[15];
  const float* t_emb     = (const float*)d_in[16];
  const float* W_rel     = (const float*)d_in[17];
  const float* b_rel     = (const float*)d_in[18];
  const float* dec_W     = (const float*)d_in[19];
  const float* dec_b     = (const float*)d_in[20];
  const float* adec_W    = (const float*)d_in[21];
  const float* adec_b    = (const float*)d_in[22];
  float* out = (float*)d_out;

  static const int E_CNT[6]    = {200000, 400000, 200000, 200000, 50000, 50000};
  static const int REL_DSTN[6] = {N_CFG, N_AST, N_CFG, N_AST, N_TEST, N_CFG};

  char* ws = (char*)d_ws;
  size_t off = 0;
  auto alloc = [&](size_t bytes) -> void* {
    void* p = ws + off;
    off += (bytes + 255) & ~(size_t)255;
    return p;
  };
  unsigned short* buf0 = (unsigned short*)alloc((size_t)NNODE * 256 * 2);
  unsigned short* buf1 = (unsigned short*)alloc((size_t)NNODE * 256 * 2);
  // bf16 A scratch, K-step-tiled [mt][kt][256][64]; max = ast: 782 tiles x 8 kt
  unsigned short* Abuf = (unsigned short*)alloc((size_t)782 * 8 * 16384 * 2);
  unsigned short* Wt   = (unsigned short*)alloc((size_t)5 * 6 * 256 * 256 * 2);
  unsigned short* WtEc = (unsigned short*)alloc((size_t)128 * 320 * 2);
  unsigned short* WtEa = (unsigned short*)alloc((size_t)128 * 320 * 2);
  float*          bsum = (float*)alloc((size_t)5 * 3 * 256 * 4);
  int* rowptr[6];
  int* srcidx[6];
  for (int r = 0; r < 6; ++r) rowptr[r] = (int*)alloc((size_t)(REL_DSTN[r] + 1) * 4);
  for (int r = 0; r < 6; ++r) srcidx[r] = (int*)alloc((size_t)E_CNT[r] * 4);
  int* cursor = (int*)alloc((size_t)(N_AST + 1) * 4);

  // weights -> bf16; bias sums
  wt_kernel<<<CDIV(5 * 6 * 256 * 256, 256), 256, 0, stream>>>(W_rel, Wt);
  wtenc_kernel<<<CDIV(128 * 320, 256), 256, 0, stream>>>(c_enc_W, WtEc);
  wtenc_kernel<<<CDIV(128 * 320, 256), 256, 0, stream>>>(a_enc_W, WtEa);
  bsum_kernel<<<CDIV(5 * 3 * 256, 256), 256, 0, stream>>>(b_rel, bsum);

  // CSR (dst-sorted) per relation
  for (int r = 0; r < 6; ++r) {
    int nd = REL_DSTN[r], E = E_CNT[r];
    const int* esrc = edges[r];
    const int* edst = edges[r] + E;
    zero_int_kernel<<<CDIV(nd, 256), 256, 0, stream>>>(cursor, nd);
    hist_kernel<<<CDIV(E, 256), 256, 0, stream>>>(edst, E, cursor);
    scan_kernel<<<1, 1024, 0, stream>>>(cursor, rowptr[r], nd);
    copy_int_kernel<<<CDIV(nd, 256), 256, 0, stream>>>(cursor, rowptr[r], nd);
    scatter_kernel<<<CDIV(E, 256), 256, 0, stream>>>(esrc, edst, E, cursor, srcidx[r]);
  }

  const size_t OFF_CFG = 0;
  const size_t OFF_AST = (size_t)N_CFG * 256;
  const size_t OFF_TST = (size_t)(N_CFG + N_AST) * 256;

  // encoders -> buf0 (bf16)
  gather_lbl_kernel<<<CDIV(N_CFG * 32, 256), 256, 0, stream>>>(c_labels, c_lbl_emb, buf0 + OFF_CFG, N_CFG);
  gather_lbl_kernel<<<CDIV(N_AST * 32, 256), 256, 0, stream>>>(a_labels, a_lbl_emb, buf0 + OFF_AST, N_AST);
  enc_mfma_kernel<<<CDIV(N_CFG, 128), 256, 0, stream>>>(c_content, N_CFG, WtEc, c_enc_b, buf0 + OFF_CFG);
  enc_mfma_kernel<<<CDIV(N_AST, 128), 256, 0, stream>>>(a_content, N_AST, WtEa, a_enc_b, buf0 + OFF_AST);
  bcast_temb_kernel<<<CDIV(N_TEST * 64, 256), 256, 0, stream>>>(t_emb, buf0 + OFF_TST);

  unsigned short* h_in = buf0;
  unsigned short* h_out = buf1;
  for (int l = 0; l < 5; ++l) {
    bool use_res = (l == 1 || l == 3);
    const unsigned short* WtL = Wt + (size_t)l * 6 * 256 * 256;
    // dst cfg: rels 0(cc: src cfg), 2(ac: src ast), 5(tc: src test); K = 768
    agg_fused_kernel<<<CDIV(N_CFG, 4), 256, 0, stream>>>(
        h_in + OFF_CFG, rowptr[0], srcidx[0],
        h_in + OFF_AST, rowptr[2], srcidx[2],
        h_in + OFF_TST, rowptr[5], srcidx[5],
        3, Abuf, 768, N_CFG);
    gemm_mfma_kernel<<<CDIV(N_CFG, 256), 512, 0, stream>>>(
        Abuf, N_CFG, 768, WtL, bsum + (size_t)(l * 3 + 0) * 256, 0, 2, 5,
        use_res ? h_in + OFF_CFG : nullptr, h_out + OFF_CFG);
    // dst ast: rels 1(aa: src ast), 3(ca: src cfg); K = 512
    agg_fused_kernel<<<CDIV(N_AST, 4), 256, 0, stream>>>(
        h_in + OFF_AST, rowptr[1], srcidx[1],
        h_in + OFF_CFG, rowptr[3], srcidx[3],
        (const unsigned short*)nullptr, (const int*)nullptr, (const int*)nullptr,
        2, Abuf, 512, N_AST);
    gemm_mfma_kernel<<<CDIV(N_AST, 256), 512, 0, stream>>>(
        Abuf, N_AST, 512, WtL, bsum + (size_t)(l * 3 + 1) * 256, 1, 3, -1,
        use_res ? h_in + OFF_AST : nullptr, h_out + OFF_AST);
    // dst test: rel 4(ct: src cfg); K = 256
    agg_fused_kernel<<<CDIV(N_TEST, 4), 256, 0, stream>>>(
        h_in + OFF_CFG, rowptr[4], srcidx[4],
        (const unsigned short*)nullptr, (const int*)nullptr, (const int*)nullptr,
        (const unsigned short*)nullptr, (const int*)nullptr, (const int*)nullptr,
        1, Abuf, 256, N_TEST);
    gemm_mfma_kernel<<<CDIV(N_TEST, 256), 512, 0, stream>>>(
        Abuf, N_TEST, 256, WtL, bsum + (size_t)(l * 3 + 2) * 256, 4, -1, -1,
        use_res ? h_in + OFF_TST : nullptr, h_out + OFF_TST);
    unsigned short* t = h_in; h_in = h_out; h_out = t;
  }

  decode2_kernel<<<CDIV(N_CFG, 4), 256, 0, stream>>>(h_in + OFF_CFG, dec_W, dec_b,
                                                     out, out + 100000, N_CFG);
  decode3_kernel<<<CDIV(N_AST, 4), 256, 0, stream>>>(h_in + OFF_AST, adec_W, adec_b,
                                                     out + 200000, out + 800000, N_AST);
}

// Round 11
// 2190.707 us; speedup vs baseline: 9.4290x; 1.2591x over previous
//
#include <hip/hip_runtime.h>
#include <stdint.h>
#include <stddef.h>

#define CDIV(a,b) (((a)+(b)-1)/(b))

#define N_CFG  50000
#define N_AST  200000
#define N_TEST 1000
#define NNODE  (N_CFG + N_AST + N_TEST)
#define E_TOT  1100000
#define ND_TOT 551000

typedef __attribute__((ext_vector_type(8))) short bf16x8;
typedef __attribute__((ext_vector_type(4))) short s16x4;
typedef __attribute__((ext_vector_type(4))) float f32x4;

__device__ __forceinline__ unsigned short f2bf(float f) {
  union { float f; unsigned int u; } x; x.f = f;
  unsigned int r = x.u + 0x7fffu + ((x.u >> 16) & 1u);   // RNE
  return (unsigned short)(r >> 16);
}
__device__ __forceinline__ float bf2f(unsigned short b) {
  union { unsigned int u; float f; } x; x.u = ((unsigned int)b) << 16;
  return x.f;
}

__device__ __forceinline__ void gload_lds16(const void* g, void* l) {
  __builtin_amdgcn_global_load_lds((const __attribute__((address_space(1))) unsigned int*)g,
                                   (__attribute__((address_space(3))) unsigned int*)l,
                                   16, 0, 0);
}

// ---------------------------------------------------------------- merged CSR build
// rel r: dst-node-count offsets co[r] into cntAll; rp offsets co[r]+r into rpAll;
// edge offsets eo[r] into the merged 1.1M edge space; srcidx offsets so[r]=eo[r].

__global__ void zero_int_kernel(int* __restrict__ p, int n) {
  int i = blockIdx.x * 256 + threadIdx.x;
  if (i < n) p[i] = 0;
}

__device__ __forceinline__ int rel_of_edge(int i, int& local) {
  if (i < 200000)  { local = i;           return 0; }
  if (i < 600000)  { local = i - 200000;  return 1; }
  if (i < 800000)  { local = i - 600000;  return 2; }
  if (i < 1000000) { local = i - 800000;  return 3; }
  if (i < 1050000) { local = i - 1000000; return 4; }
  local = i - 1050000; return 5;
}

__global__ void hist6_kernel(const int* __restrict__ d0, const int* __restrict__ d1,
                             const int* __restrict__ d2, const int* __restrict__ d3,
                             const int* __restrict__ d4, const int* __restrict__ d5,
                             int* __restrict__ cntAll) {
  int i = blockIdx.x * 256 + threadIdx.x;
  if (i >= E_TOT) return;
  int local; int r = rel_of_edge(i, local);
  const int* dp[6] = {d0, d1, d2, d3, d4, d5};
  const int co[6] = {0, 50000, 250000, 300000, 500000, 501000};
  atomicAdd(&cntAll[co[r] + dp[r][local]], 1);
}

// 6 concurrent single-block scans (block r scans rel r): rp[0]=0, rp[i+1]=prefix
__global__ __launch_bounds__(1024) void scan6_kernel(const int* __restrict__ cntAll,
                                                     int* __restrict__ rpAll) {
  const int nd[6] = {N_CFG, N_AST, N_CFG, N_AST, N_TEST, N_CFG};
  const int co[6] = {0, 50000, 250000, 300000, 500000, 501000};
  int rrel = blockIdx.x;
  const int* cnt = cntAll + co[rrel];
  int* rp = rpAll + co[rrel] + rrel;
  int n = nd[rrel];
  __shared__ int wsum[16];
  __shared__ int carry;
  int tid = threadIdx.x;
  int lane = tid & 63, wid = tid >> 6;
  if (tid == 0) { carry = 0; rp[0] = 0; }
  __syncthreads();
  for (int base = 0; base < n; base += 4096) {
    int i0 = base + tid * 4;
    int4 v = make_int4(0, 0, 0, 0);
    if (i0 + 3 < n) {
      v = *(const int4*)(cnt + i0);
    } else if (i0 < n) {
      v.x = cnt[i0];
      if (i0 + 1 < n) v.y = cnt[i0 + 1];
      if (i0 + 2 < n) v.z = cnt[i0 + 2];
    }
    int s1 = v.x + v.y, s2 = s1 + v.z, s3 = s2 + v.w;
    int s = s3;
    #pragma unroll
    for (int o = 1; o < 64; o <<= 1) {
      int t = __shfl_up(s, o, 64);
      if (lane >= o) s += t;
    }
    if (lane == 63) wsum[wid] = s;
    __syncthreads();
    if (wid == 0) {
      int x = (lane < 16) ? wsum[lane] : 0;
      #pragma unroll
      for (int o = 1; o < 16; o <<= 1) {
        int t = __shfl_up(x, o, 64);
        if (lane >= o) x += t;
      }
      if (lane < 16) wsum[lane] = x;
    }
    __syncthreads();
    int off = carry + (wid > 0 ? wsum[wid - 1] : 0) + (s - s3);
    if (i0 < n)     rp[i0 + 1] = off + v.x;
    if (i0 + 1 < n) rp[i0 + 2] = off + s1;
    if (i0 + 2 < n) rp[i0 + 3] = off + s2;
    if (i0 + 3 < n) rp[i0 + 4] = off + s3;
    __syncthreads();
    if (tid == 0) carry += wsum[15];
    __syncthreads();
  }
}

// cursorAll[i] = rp start for that dst node (cursorAll aliases cntAll storage)
__global__ void cursor6_kernel(int* __restrict__ cursorAll, const int* __restrict__ rpAll) {
  int i = blockIdx.x * 256 + threadIdx.x;
  if (i >= ND_TOT) return;
  int r = (i < 50000) ? 0 : (i < 250000) ? 1 : (i < 300000) ? 2
        : (i < 500000) ? 3 : (i < 501000) ? 4 : 5;
  cursorAll[i] = rpAll[i + r];
}

__global__ void scatter6_kernel(const int* __restrict__ s0, const int* __restrict__ s1,
                                const int* __restrict__ s2, const int* __restrict__ s3,
                                const int* __restrict__ s4, const int* __restrict__ s5,
                                const int* __restrict__ d0, const int* __restrict__ d1,
                                const int* __restrict__ d2, const int* __restrict__ d3,
                                const int* __restrict__ d4, const int* __restrict__ d5,
                                int* __restrict__ cursorAll, int* __restrict__ siAll) {
  int i = blockIdx.x * 256 + threadIdx.x;
  if (i >= E_TOT) return;
  int local; int r = rel_of_edge(i, local);
  const int* sp[6] = {s0, s1, s2, s3, s4, s5};
  const int* dp[6] = {d0, d1, d2, d3, d4, d5};
  const int co[6] = {0, 50000, 250000, 300000, 500000, 501000};
  const int eo[6] = {0, 200000, 600000, 800000, 1000000, 1050000};
  int p = atomicAdd(&cursorAll[co[r] + dp[r][local]], 1);
  siAll[eo[r] + p] = sp[r][local];
}

// ---------------------------------------------------------------- encoders (h stored bf16)
__global__ void gather_lbl_kernel(const int* __restrict__ labels, const float* __restrict__ emb,
                                  unsigned short* __restrict__ h, int n) {
  int i = blockIdx.x * 256 + threadIdx.x;
  int node = i >> 5, l = i & 31;
  if (node < n) {
    float4 v = ((const float4*)(emb + (size_t)labels[node] * 128))[l];
    s16x4 o;
    o.x = (short)f2bf(v.x); o.y = (short)f2bf(v.y);
    o.z = (short)f2bf(v.z); o.w = (short)f2bf(v.w);
    *(s16x4*)(h + (size_t)node * 256 + l * 4) = o;
  }
}

__global__ void bcast_temb_kernel(const float* __restrict__ t, unsigned short* __restrict__ h) {
  int i = blockIdx.x * 256 + threadIdx.x;
  int node = i >> 6, l = i & 63;
  if (node < N_TEST) {
    float4 v = ((const float4*)t)[l];
    s16x4 o;
    o.x = (short)f2bf(v.x); o.y = (short)f2bf(v.y);
    o.z = (short)f2bf(v.z); o.w = (short)f2bf(v.w);
    *(s16x4*)(h + (size_t)node * 256 + l * 4) = o;
  }
}

// enc W fp32 [300][128] -> bf16 [128 n][320 k] zero-padded
__global__ void wtenc_kernel(const float* __restrict__ W, unsigned short* __restrict__ Wt) {
  int i = blockIdx.x * 256 + threadIdx.x;
  if (i >= 128 * 320) return;
  int k = i % 320, n = i / 320;
  Wt[i] = (k < 300) ? f2bf(W[(size_t)k * 128 + n]) : (unsigned short)0;
}

// content[M,300] @ W[300,128] + b -> bf16 h[row*256 + 128 + col]
__global__ __launch_bounds__(256) void enc_mfma_kernel(
    const float* __restrict__ A, int M,
    const unsigned short* __restrict__ WtE,   // [128][320] bf16
    const float* __restrict__ bias,           // [128] fp32
    unsigned short* __restrict__ h) {
  __shared__ __align__(16) unsigned short As[2][8192];
  __shared__ __align__(16) unsigned short Bs[2][8192];
  int tid = threadIdx.x, lane = tid & 63, wid = tid >> 6;
  int gm0 = blockIdx.x * 128;

  int wr = wid >> 1, wc = wid & 1;
  f32x4 acc[4][4];
  #pragma unroll
  for (int mi = 0; mi < 4; ++mi)
    #pragma unroll
    for (int ni = 0; ni < 4; ++ni) acc[mi][ni] = (f32x4){0.f, 0.f, 0.f, 0.f};

  auto stageB = [&](int buf, int kt) {
    int k0 = kt * 64;
    #pragma unroll
    for (int j = 0; j < 4; ++j) {
      int q = tid * 4 + j;                 // 0..1023 -> rows 0..127
      int row = q >> 3, sp = q & 7;
      int sgl = sp ^ (row & 7);
      *(uint4*)&Bs[buf][row * 64 + sp * 8] =
          *(const uint4*)(WtE + (size_t)row * 320 + k0 + sgl * 8);
    }
  };
  auto stageA = [&](int buf, int kt) {
    int k0 = kt * 64;
    #pragma unroll
    for (int j = 0; j < 4; ++j) {
      int q = tid * 4 + j;
      int row = q >> 3, s = q & 7;
      int grow = gm0 + row;
      int k = k0 + s * 8;
      float v[8];
      if (grow < M && k + 8 <= 300) {
        float4 u0 = *(const float4*)(A + (size_t)grow * 300 + k);
        float4 u1 = *(const float4*)(A + (size_t)grow * 300 + k + 4);
        v[0] = u0.x; v[1] = u0.y; v[2] = u0.z; v[3] = u0.w;
        v[4] = u1.x; v[5] = u1.y; v[6] = u1.z; v[7] = u1.w;
      } else {
        #pragma unroll
        for (int e = 0; e < 8; ++e)
          v[e] = (grow < M && k + e < 300) ? A[(size_t)grow * 300 + k + e] : 0.f;
      }
      bf16x8 o;
      #pragma unroll
      for (int e = 0; e < 8; ++e) o[e] = (short)f2bf(v[e]);
      *(bf16x8*)&As[buf][row * 64 + ((s ^ (row & 7)) * 8)] = o;
    }
  };

  const int nkt = 5;   // 320 / 64
  stageA(0, 0); stageB(0, 0);
  __syncthreads();
  for (int kt = 0; kt < nkt; ++kt) {
    int cur = kt & 1;
    if (kt + 1 < nkt) { stageA(cur ^ 1, kt + 1); stageB(cur ^ 1, kt + 1); }
    #pragma unroll
    for (int kk = 0; kk < 2; ++kk) {
      bf16x8 af[4], bfr[4];
      int slBase = kk * 4 + (lane >> 4);
      #pragma unroll
      for (int mi = 0; mi < 4; ++mi) {
        int row = wr * 64 + mi * 16 + (lane & 15);
        af[mi] = *(const bf16x8*)&As[cur][row * 64 + ((slBase ^ (row & 7)) * 8)];
      }
      #pragma unroll
      for (int ni = 0; ni < 4; ++ni) {
        int row = wc * 64 + ni * 16 + (lane & 15);
        bfr[ni] = *(const bf16x8*)&Bs[cur][row * 64 + ((slBase ^ (row & 7)) * 8)];
      }
      __builtin_amdgcn_s_setprio(1);
      #pragma unroll
      for (int mi = 0; mi < 4; ++mi)
        #pragma unroll
        for (int ni = 0; ni < 4; ++ni)
          acc[mi][ni] = __builtin_amdgcn_mfma_f32_16x16x32_bf16(bfr[ni], af[mi], acc[mi][ni], 0, 0, 0);
      __builtin_amdgcn_s_setprio(0);
    }
    __syncthreads();
  }

  float4 b4[4];
  #pragma unroll
  for (int ni = 0; ni < 4; ++ni)
    b4[ni] = *(const float4*)(bias + wc * 64 + ni * 16 + (lane >> 4) * 4);
  #pragma unroll
  for (int mi = 0; mi < 4; ++mi) {
    int m = gm0 + wr * 64 + mi * 16 + (lane & 15);
    if (m >= M) continue;
    #pragma unroll
    for (int ni = 0; ni < 4; ++ni) {
      f32x4 v = acc[mi][ni];
      int nb = wc * 64 + ni * 16 + (lane >> 4) * 4;
      s16x4 o;
      o.x = (short)f2bf(v[0] + b4[ni].x);
      o.y = (short)f2bf(v[1] + b4[ni].y);
      o.z = (short)f2bf(v[2] + b4[ni].z);
      o.w = (short)f2bf(v[3] + b4[ni].w);
      *(s16x4*)(h + (size_t)m * 256 + 128 + nb) = o;
    }
  }
}

// ---------------------------------------------------------------- W -> bf16 transpose
__global__ void wt_kernel(const float* __restrict__ W, unsigned short* __restrict__ Wt) {
  int i = blockIdx.x * 256 + threadIdx.x;
  int k = i & 255, n = (i >> 8) & 255, lr = i >> 16;
  Wt[i] = f2bf(W[((size_t)lr * 256 + k) * 256 + n]);
}

// summed bias per (layer, dst-type): bsum[l][dt][256], dt: 0=cfg 1=ast 2=test
__global__ void bsum_kernel(const float* __restrict__ brel, float* __restrict__ bsum) {
  int i = blockIdx.x * 256 + threadIdx.x;
  if (i >= 5 * 3 * 256) return;
  int n = i & 255, dt = (i >> 8) % 3, l = i / (3 * 256);
  float s;
  if (dt == 0)      s = brel[((size_t)l * 6 + 0) * 256 + n] + brel[((size_t)l * 6 + 2) * 256 + n] + brel[((size_t)l * 6 + 5) * 256 + n];
  else if (dt == 1) s = brel[((size_t)l * 6 + 1) * 256 + n] + brel[((size_t)l * 6 + 3) * 256 + n];
  else              s = brel[((size_t)l * 6 + 4) * 256 + n];
  bsum[i] = s;
}

// ---------------------------------------------------------------- merged per-layer aggregation
// One launch covers all 3 dst types: blocks [0,50000)=ast, [50000,62500)=cfg, [62500,62750)=test.
// Wave per dst node; half-waves process 2 edges (16B/lane), shfl_xor(32) reduce.
// Output K-step-tiled: A[mt][kt][256][64].
__global__ void agg_all_kernel(
    const unsigned short* __restrict__ hC, const unsigned short* __restrict__ hA,
    const unsigned short* __restrict__ hT,
    const int* __restrict__ rp0, const int* __restrict__ si0,
    const int* __restrict__ rp1, const int* __restrict__ si1,
    const int* __restrict__ rp2, const int* __restrict__ si2,
    const int* __restrict__ rp3, const int* __restrict__ si3,
    const int* __restrict__ rp4, const int* __restrict__ si4,
    const int* __restrict__ rp5, const int* __restrict__ si5,
    unsigned short* __restrict__ Aast, unsigned short* __restrict__ Acfg,
    unsigned short* __restrict__ Atst) {
  int b = blockIdx.x;
  int wv = threadIdx.x >> 6, lane = threadIdx.x & 63;
  int half = lane >> 5, l32 = lane & 31;

  int w, nkt;
  unsigned short* A;
  const unsigned short* hh[3]; const int* rpp[3]; const int* sii[3]; int nrel;
  if (b < 50000) {            // ast dst: rels 1 (src ast), 3 (src cfg); K=512
    w = b * 4 + wv; nkt = 8; A = Aast; nrel = 2;
    hh[0] = hA; rpp[0] = rp1; sii[0] = si1;
    hh[1] = hC; rpp[1] = rp3; sii[1] = si3;
    hh[2] = hC; rpp[2] = rp3; sii[2] = si3;
  } else if (b < 62500) {     // cfg dst: rels 0 (cfg), 2 (ast), 5 (test); K=768
    w = (b - 50000) * 4 + wv; nkt = 12; A = Acfg; nrel = 3;
    hh[0] = hC; rpp[0] = rp0; sii[0] = si0;
    hh[1] = hA; rpp[1] = rp2; sii[1] = si2;
    hh[2] = hT; rpp[2] = rp5; sii[2] = si5;
  } else {                    // test dst: rel 4 (src cfg); K=256
    w = (b - 62500) * 4 + wv; nkt = 4; A = Atst; nrel = 1;
    hh[0] = hC; rpp[0] = rp4; sii[0] = si4;
    hh[1] = hC; rpp[1] = rp4; sii[1] = si4;
    hh[2] = hC; rpp[2] = rp4; sii[2] = si4;
  }

  size_t tilebase = ((size_t)(w >> 8) * nkt * 256 + (w & 255)) * 64;   // + kt*16384
  #pragma unroll 1
  for (int rr = 0; rr < nrel; ++rr) {
    const unsigned short* h = hh[rr];
    const int* rp = rpp[rr];
    const int* si = sii[rr];
    int bb = rp[w], ee = rp[w + 1];
    float acc[8] = {0.f, 0.f, 0.f, 0.f, 0.f, 0.f, 0.f, 0.f};
    for (int i = bb + half; i < ee; i += 2) {
      bf16x8 v = *(const bf16x8*)(h + (size_t)si[i] * 256 + l32 * 8);
      #pragma unroll
      for (int k = 0; k < 8; ++k) acc[k] += bf2f((unsigned short)v[k]);
    }
    #pragma unroll
    for (int k = 0; k < 8; ++k) acc[k] += __shfl_xor(acc[k], 32, 64);
    if (half == 0) {
      bf16x8 o;
      #pragma unroll
      for (int k = 0; k < 8; ++k) o[k] = (short)f2bf(acc[k]);
      int kt = rr * 4 + (l32 >> 3);
      int cc = (l32 & 7) * 8;
      *(bf16x8*)(A + tilebase + (size_t)kt * 16384 + cc) = o;
    }
  }
}

// ---------------------------------------------------------------- merged per-layer MFMA GEMM
// Blocks [0,782)=ast, [782,978)=cfg, [978,982)=test. BM=256, BN=256, 512 thr / 8 waves.
// A K-step-tiled (contiguous 32 KB stage). Double-buffered A+B (128 KB LDS),
// counted-vmcnt(8) pipeline; never vmcnt(0) mid-loop. Round-7 direct epilogue
// (round-10 LDS restage regressed: WRITE 105->205 MB partial-line evictions).
__global__ __launch_bounds__(512, 2) void gemm_all_kernel(
    const unsigned short* __restrict__ Aast, const unsigned short* __restrict__ Acfg,
    const unsigned short* __restrict__ Atst,
    const unsigned short* __restrict__ WtL,   // [6][256 n][256 k] bf16, this layer
    const float* __restrict__ bsumL,          // [3][256] summed bias, this layer
    const unsigned short* __restrict__ resA, const unsigned short* __restrict__ resC,
    const unsigned short* __restrict__ resT,
    unsigned short* __restrict__ outA, unsigned short* __restrict__ outC,
    unsigned short* __restrict__ outT) {
  __shared__ __align__(16) unsigned short AsL[2][16384];
  __shared__ __align__(16) unsigned short BsL[2][16384];
  int tid = threadIdx.x, lane = tid & 63, wid = tid >> 6;
  int b = blockIdx.x;

  int mtile, M, nkt, r0, r1, r2, dt;
  const unsigned short* A;
  const unsigned short* residual;
  unsigned short* out;
  if (b < 782) {
    mtile = b;       A = Aast; M = N_AST;  nkt = 8;  r0 = 1; r1 = 3; r2 = 3; dt = 1;
    residual = resA; out = outA;
  } else if (b < 978) {
    mtile = b - 782; A = Acfg; M = N_CFG;  nkt = 12; r0 = 0; r1 = 2; r2 = 5; dt = 0;
    residual = resC; out = outC;
  } else {
    mtile = b - 978; A = Atst; M = N_TEST; nkt = 4;  r0 = 4; r1 = 4; r2 = 4; dt = 2;
    residual = resT; out = outT;
  }
  int gm0 = mtile * 256;
  int rels[3] = {r0, r1, r2};
  const float* bsum = bsumL + dt * 256;

  int wr = wid >> 1, wc = wid & 1;         // 4 (M) x 2 (N) waves
  f32x4 acc[4][8];
  #pragma unroll
  for (int mi = 0; mi < 4; ++mi)
    #pragma unroll
    for (int ni = 0; ni < 8; ++ni) acc[mi][ni] = (f32x4){0.f, 0.f, 0.f, 0.f};

  auto stageA = [&](int buf, int kt) {
    if (kt > nkt - 1) kt = nkt - 1;        // clamp: uniform vmcnt counting at tail
    const unsigned short* base = A + ((size_t)mtile * nkt + kt) * 16384;
    #pragma unroll
    for (int i = 0; i < 4; ++i) {
      int instr = wid * 4 + i;
      int P = instr * 64 + lane;
      int row = P >> 3, sp = P & 7;
      int s = sp ^ (row & 7);
      gload_lds16(base + row * 64 + s * 8, &AsL[buf][instr * 512]);
    }
  };
  auto stageB = [&](int buf, int kt) {
    if (kt > nkt - 1) kt = nkt - 1;
    int k0 = kt * 64;
    #pragma unroll
    for (int i = 0; i < 4; ++i) {
      int instr = wid * 4 + i;
      int P = instr * 64 + lane;
      int row = P >> 3, sp = P & 7;
      int s = sp ^ (row & 7);
      gload_lds16(WtL + ((size_t)rels[k0 >> 8] * 256 + row) * 256 + (k0 & 255) + s * 8,
                  &BsL[buf][instr * 512]);
    }
  };

  // prologue: tiles 0,1 into bufs 0,1 (16 loads/wave); vmcnt(8) forces tile0
  stageA(0, 0); stageB(0, 0); stageA(1, 1); stageB(1, 1);
  asm volatile("s_waitcnt vmcnt(8)" ::: "memory");
  __builtin_amdgcn_s_barrier();

  int cb = 0;
  for (int kt = 0; kt < nkt; ++kt) {
    #pragma unroll
    for (int kk = 0; kk < 2; ++kk) {
      bf16x8 af[4], bfr[8];
      int slBase = kk * 4 + (lane >> 4);
      #pragma unroll
      for (int mi = 0; mi < 4; ++mi) {
        int row = wr * 64 + mi * 16 + (lane & 15);
        af[mi] = *(const bf16x8*)&AsL[cb][row * 64 + ((slBase ^ (row & 7)) * 8)];
      }
      #pragma unroll
      for (int ni = 0; ni < 8; ++ni) {
        int row = wc * 128 + ni * 16 + (lane & 15);
        bfr[ni] = *(const bf16x8*)&BsL[cb][row * 64 + ((slBase ^ (row & 7)) * 8)];
      }
      __builtin_amdgcn_s_setprio(1);
      #pragma unroll
      for (int mi = 0; mi < 4; ++mi)
        #pragma unroll
        for (int ni = 0; ni < 8; ++ni)
          acc[mi][ni] = __builtin_amdgcn_mfma_f32_16x16x32_bf16(bfr[ni], af[mi], acc[mi][ni], 0, 0, 0);
      __builtin_amdgcn_s_setprio(0);
    }
    if (kt + 1 < nkt) {
      __builtin_amdgcn_s_barrier();        // all waves done reading buffer cb
      stageB(cb, kt + 2);                  // overwrite cb with tile kt+2
      stageA(cb, kt + 2);
      asm volatile("s_waitcnt vmcnt(8)" ::: "memory");   // tile kt+1's loads landed
      __builtin_amdgcn_s_barrier();
      cb ^= 1;
    }
  }
  asm volatile("s_waitcnt vmcnt(0)" ::: "memory");       // drain clamped tail loads
  __builtin_amdgcn_sched_barrier(0);

  // epilogue (round-7 form: swapped layout, lane holds 4 consecutive cols of one row)
  float4 b4[8];
  #pragma unroll
  for (int ni = 0; ni < 8; ++ni)
    b4[ni] = *(const float4*)(bsum + wc * 128 + ni * 16 + (lane >> 4) * 4);
  #pragma unroll
  for (int mi = 0; mi < 4; ++mi) {
    int m = gm0 + wr * 64 + mi * 16 + (lane & 15);
    if (m >= M) continue;
    #pragma unroll
    for (int ni = 0; ni < 8; ++ni) {
      f32x4 v = acc[mi][ni];
      int nb = wc * 128 + ni * 16 + (lane >> 4) * 4;
      float x0 = fmaxf(v[0] + b4[ni].x, 0.f);
      float x1 = fmaxf(v[1] + b4[ni].y, 0.f);
      float x2 = fmaxf(v[2] + b4[ni].z, 0.f);
      float x3 = fmaxf(v[3] + b4[ni].w, 0.f);
      if (residual) {
        s16x4 rv = *(const s16x4*)(residual + (size_t)m * 256 + nb);
        x0 += bf2f((unsigned short)rv.x); x1 += bf2f((unsigned short)rv.y);
        x2 += bf2f((unsigned short)rv.z); x3 += bf2f((unsigned short)rv.w);
      }
      s16x4 o;
      o.x = (short)f2bf(x0); o.y = (short)f2bf(x1);
      o.z = (short)f2bf(x2); o.w = (short)f2bf(x3);
      *(s16x4*)(out + (size_t)m * 256 + nb) = o;
    }
  }
}

// ---------------------------------------------------------------- decoders (bf16 h in, fp32 out)
__global__ void decode2_kernel(const unsigned short* __restrict__ h, const float* __restrict__ W,
                               const float* __restrict__ b, float* __restrict__ logits,
                               float* __restrict__ soft, int n) {
  int w = (blockIdx.x * blockDim.x + threadIdx.x) >> 6;
  int lane = threadIdx.x & 63;
  if (w >= n) return;
  s16x4 hv = *(const s16x4*)(h + (size_t)w * 256 + lane * 4);
  float x0 = bf2f((unsigned short)hv.x), x1 = bf2f((unsigned short)hv.y);
  float x2 = bf2f((unsigned short)hv.z), x3 = bf2f((unsigned short)hv.w);
  int k = lane * 4;
  float l0 = x0 * W[(k + 0) * 2 + 0] + x1 * W[(k + 1) * 2 + 0] +
             x2 * W[(k + 2) * 2 + 0] + x3 * W[(k + 3) * 2 + 0];
  float l1 = x0 * W[(k + 0) * 2 + 1] + x1 * W[(k + 1) * 2 + 1] +
             x2 * W[(k + 2) * 2 + 1] + x3 * W[(k + 3) * 2 + 1];
  #pragma unroll
  for (int m = 1; m < 64; m <<= 1) {
    l0 += __shfl_xor(l0, m, 64);
    l1 += __shfl_xor(l1, m, 64);
  }
  if (lane == 0) {
    l0 += b[0]; l1 += b[1];
    float mx = fmaxf(l0, l1);
    float e0 = expf(l0 - mx), e1 = expf(l1 - mx);
    float s = e0 + e1;
    logits[(size_t)w * 2 + 0] = l0;
    logits[(size_t)w * 2 + 1] = l1;
    soft[(size_t)w * 2 + 0] = e0 / s;
    soft[(size_t)w * 2 + 1] = e1 / s;
  }
}

__global__ void decode3_kernel(const unsigned short* __restrict__ h, const float* __restrict__ W,
                               const float* __restrict__ b, float* __restrict__ logits,
                               float* __restrict__ soft, int n) {
  int w = (blockIdx.x * blockDim.x + threadIdx.x) >> 6;
  int lane = threadIdx.x & 63;
  if (w >= n) return;
  s16x4 hv = *(const s16x4*)(h + (size_t)w * 256 + lane * 4);
  float x0 = bf2f((unsigned short)hv.x), x1 = bf2f((unsigned short)hv.y);
  float x2 = bf2f((unsigned short)hv.z), x3 = bf2f((unsigned short)hv.w);
  int k = lane * 4;
  float l0 = x0 * W[(k + 0) * 3 + 0] + x1 * W[(k + 1) * 3 + 0] +
             x2 * W[(k + 2) * 3 + 0] + x3 * W[(k + 3) * 3 + 0];
  float l1 = x0 * W[(k + 0) * 3 + 1] + x1 * W[(k + 1) * 3 + 1] +
             x2 * W[(k + 2) * 3 + 1] + x3 * W[(k + 3) * 3 + 1];
  float l2 = x0 * W[(k + 0) * 3 + 2] + x1 * W[(k + 1) * 3 + 2] +
             x2 * W[(k + 2) * 3 + 2] + x3 * W[(k + 3) * 3 + 2];
  #pragma unroll
  for (int m = 1; m < 64; m <<= 1) {
    l0 += __shfl_xor(l0, m, 64);
    l1 += __shfl_xor(l1, m, 64);
    l2 += __shfl_xor(l2, m, 64);
  }
  if (lane == 0) {
    l0 += b[0]; l1 += b[1]; l2 += b[2];
    float mx = fmaxf(fmaxf(l0, l1), l2);
    float e0 = expf(l0 - mx), e1 = expf(l1 - mx), e2 = expf(l2 - mx);
    float s = e0 + e1 + e2;
    logits[(size_t)w * 3 + 0] = l0;
    logits[(size_t)w * 3 + 1] = l1;
    logits[(size_t)w * 3 + 2] = l2;
    soft[(size_t)w * 3 + 0] = e0 / s;
    soft[(size_t)w * 3 + 1] = e1 / s;
    soft[(size_t)w * 3 + 2] = e2 / s;
  }
}

// ---------------------------------------------------------------- host
extern "C" void kernel_launch(void* const* d_in, const int* in_sizes, int n_in,
                              void* d_out, int out_size, void* d_ws, size_t ws_size,
                              hipStream_t stream) {
  (void)in_sizes; (void)n_in; (void)out_size; (void)ws_size;
  const int*   c_labels  = (const int*)  d_in[0];
  const float* c_content = (const float*)d_in[1];
  const int*   a_labels  = (const int*)  d_in[2];
  const float* a_content = (const float*)d_in[3];
  const int*   edges[6];
  for (int r = 0; r < 6; ++r) edges[r] = (const int*)d_in[4 + r];
  const float* c_lbl_emb = (const float*)d_in[10];
  const float* c_enc_W   = (const float*)d_in[11];
  const float* c_enc_b   = (const float*)d_in[12];
  const float* a_lbl_emb = (const float*)d_in[13];
  const float* a_enc_W   = (const float*)d_in[14];
  const float* a_enc_b   = (const float*)d_in[15];
  const float* t_emb     = (const float*)d_in[16];
  const float* W_rel     = (const float*)d_in[17];
  const float* b_rel     = (const float*)d_in[18];
  const float* dec_W     = (const float*)d_in[19];
  const float* dec_b     = (const float*)d_in[20];
  const float* adec_W    = (const float*)d_in[21];
  const float* adec_b    = (const float*)d_in[22];
  float* out = (float*)d_out;

  static const int E_CNT[6] = {200000, 400000, 200000, 200000, 50000, 50000};
  static const int RO[6]    = {0, 50001, 250002, 300003, 500004, 501005};  // rp offsets
  static const int SO[6]    = {0, 200000, 600000, 800000, 1000000, 1050000};

  char* ws = (char*)d_ws;
  size_t off = 0;
  auto alloc = [&](size_t bytes) -> void* {
    void* p = ws + off;
    off += (bytes + 255) & ~(size_t)255;
    return p;
  };
  unsigned short* buf0 = (unsigned short*)alloc((size_t)NNODE * 256 * 2);
  unsigned short* buf1 = (unsigned short*)alloc((size_t)NNODE * 256 * 2);
  unsigned short* Aast = (unsigned short*)alloc((size_t)782 * 8 * 16384 * 2);
  unsigned short* Acfg = (unsigned short*)alloc((size_t)196 * 12 * 16384 * 2);
  unsigned short* Atst = (unsigned short*)alloc((size_t)4 * 4 * 16384 * 2);
  unsigned short* Wt   = (unsigned short*)alloc((size_t)5 * 6 * 256 * 256 * 2);
  unsigned short* WtEc = (unsigned short*)alloc((size_t)128 * 320 * 2);
  unsigned short* WtEa = (unsigned short*)alloc((size_t)128 * 320 * 2);
  float*          bsum = (float*)alloc((size_t)5 * 3 * 256 * 4);
  int* cntAll = (int*)alloc((size_t)ND_TOT * 4);          // also reused as cursor
  int* rpAll  = (int*)alloc((size_t)(ND_TOT + 6) * 4);
  int* siAll  = (int*)alloc((size_t)E_TOT * 4);

  // weights -> bf16; bias sums
  wt_kernel<<<CDIV(5 * 6 * 256 * 256, 256), 256, 0, stream>>>(W_rel, Wt);
  wtenc_kernel<<<CDIV(128 * 320, 256), 256, 0, stream>>>(c_enc_W, WtEc);
  wtenc_kernel<<<CDIV(128 * 320, 256), 256, 0, stream>>>(a_enc_W, WtEa);
  bsum_kernel<<<CDIV(5 * 3 * 256, 256), 256, 0, stream>>>(b_rel, bsum);

  // merged CSR build (5 launches; 6 scans run as 6 concurrent blocks)
  const int* d0 = edges[0] + E_CNT[0]; const int* d1 = edges[1] + E_CNT[1];
  const int* d2 = edges[2] + E_CNT[2]; const int* d3 = edges[3] + E_CNT[3];
  const int* d4 = edges[4] + E_CNT[4]; const int* d5 = edges[5] + E_CNT[5];
  zero_int_kernel<<<CDIV(ND_TOT, 256), 256, 0, stream>>>(cntAll, ND_TOT);
  hist6_kernel<<<CDIV(E_TOT, 256), 256, 0, stream>>>(d0, d1, d2, d3, d4, d5, cntAll);
  scan6_kernel<<<6, 1024, 0, stream>>>(cntAll, rpAll);
  cursor6_kernel<<<CDIV(ND_TOT, 256), 256, 0, stream>>>(cntAll, rpAll);
  scatter6_kernel<<<CDIV(E_TOT, 256), 256, 0, stream>>>(
      edges[0], edges[1], edges[2], edges[3], edges[4], edges[5],
      d0, d1, d2, d3, d4, d5, cntAll, siAll);

  const size_t OFF_CFG = 0;
  const size_t OFF_AST = (size_t)N_CFG * 256;
  const size_t OFF_TST = (size_t)(N_CFG + N_AST) * 256;

  // encoders -> buf0 (bf16)
  gather_lbl_kernel<<<CDIV(N_CFG * 32, 256), 256, 0, stream>>>(c_labels, c_lbl_emb, buf0 + OFF_CFG, N_CFG);
  gather_lbl_kernel<<<CDIV(N_AST * 32, 256), 256, 0, stream>>>(a_labels, a_lbl_emb, buf0 + OFF_AST, N_AST);
  enc_mfma_kernel<<<CDIV(N_CFG, 128), 256, 0, stream>>>(c_content, N_CFG, WtEc, c_enc_b, buf0 + OFF_CFG);
  enc_mfma_kernel<<<CDIV(N_AST, 128), 256, 0, stream>>>(a_content, N_AST, WtEa, a_enc_b, buf0 + OFF_AST);
  bcast_temb_kernel<<<CDIV(N_TEST * 64, 256), 256, 0, stream>>>(t_emb, buf0 + OFF_TST);

  unsigned short* h_in = buf0;
  unsigned short* h_out = buf1;
  for (int l = 0; l < 5; ++l) {
    bool use_res = (l == 1 || l == 3);
    const unsigned short* WtL = Wt + (size_t)l * 6 * 256 * 256;
    const float* bsumL = bsum + (size_t)l * 3 * 256;
    agg_all_kernel<<<62750, 256, 0, stream>>>(
        h_in + OFF_CFG, h_in + OFF_AST, h_in + OFF_TST,
        rpAll + RO[0], siAll + SO[0], rpAll + RO[1], siAll + SO[1],
        rpAll + RO[2], siAll + SO[2], rpAll + RO[3], siAll + SO[3],
        rpAll + RO[4], siAll + SO[4], rpAll + RO[5], siAll + SO[5],
        Aast, Acfg, Atst);
    gemm_all_kernel<<<982, 512, 0, stream>>>(
        Aast, Acfg, Atst, WtL, bsumL,
        use_res ? h_in + OFF_AST : nullptr,
        use_res ? h_in + OFF_CFG : nullptr,
        use_res ? h_in + OFF_TST : nullptr,
        h_out + OFF_AST, h_out + OFF_CFG, h_out + OFF_TST);
    unsigned short* t = h_in; h_in = h_out; h_out = t;
  }

  decode2_kernel<<<CDIV(N_CFG, 4), 256, 0, stream>>>(h_in + OFF_CFG, dec_W, dec_b,
                                                     out, out + 100000, N_CFG);
  decode3_kernel<<<CDIV(N_AST, 4), 256, 0, stream>>>(h_in + OFF_AST, adec_W, adec_b,
                                                     out + 200000, out + 800000, N_AST);
}

// Round 13
// 1961.109 us; speedup vs baseline: 10.5329x; 1.1171x over previous
//
#include <hip/hip_runtime.h>
#include <stdint.h>
#include <stddef.h>

#define CDIV(a,b) (((a)+(b)-1)/(b))

#define N_CFG  50000
#define N_AST  200000
#define N_TEST 1000
#define NNODE  (N_CFG + N_AST + N_TEST)
#define E_TOT  1100000
#define ND_TOT 551000

typedef __attribute__((ext_vector_type(8))) short bf16x8;
typedef __attribute__((ext_vector_type(4))) short s16x4;
typedef __attribute__((ext_vector_type(4))) float f32x4;
typedef __attribute__((ext_vector_type(4))) unsigned int u32x4;

__device__ __forceinline__ unsigned short f2bf(float f) {
  union { float f; unsigned int u; } x; x.f = f;
  unsigned int r = x.u + 0x7fffu + ((x.u >> 16) & 1u);   // RNE
  return (unsigned short)(r >> 16);
}
__device__ __forceinline__ float bf2f(unsigned short b) {
  union { unsigned int u; float f; } x; x.u = ((unsigned int)b) << 16;
  return x.f;
}

__device__ __forceinline__ void gload_lds16(const void* g, void* l) {
  __builtin_amdgcn_global_load_lds((const __attribute__((address_space(1))) unsigned int*)g,
                                   (__attribute__((address_space(3))) unsigned int*)l,
                                   16, 0, 0);
}

// ---------------------------------------------------------------- merged CSR build
__global__ void zero_int_kernel(int* __restrict__ p, int n) {
  int i = blockIdx.x * 256 + threadIdx.x;
  if (i < n) p[i] = 0;
}

__device__ __forceinline__ int rel_of_edge(int i, int& local) {
  if (i < 200000)  { local = i;           return 0; }
  if (i < 600000)  { local = i - 200000;  return 1; }
  if (i < 800000)  { local = i - 600000;  return 2; }
  if (i < 1000000) { local = i - 800000;  return 3; }
  if (i < 1050000) { local = i - 1000000; return 4; }
  local = i - 1050000; return 5;
}

__global__ void hist6_kernel(const int* __restrict__ d0, const int* __restrict__ d1,
                             const int* __restrict__ d2, const int* __restrict__ d3,
                             const int* __restrict__ d4, const int* __restrict__ d5,
                             int* __restrict__ cntAll) {
  int i = blockIdx.x * 256 + threadIdx.x;
  if (i >= E_TOT) return;
  int local; int r = rel_of_edge(i, local);
  const int* dp[6] = {d0, d1, d2, d3, d4, d5};
  const int co[6] = {0, 50000, 250000, 300000, 500000, 501000};
  atomicAdd(&cntAll[co[r] + dp[r][local]], 1);
}

// 6 concurrent single-block scans (block r scans rel r)
__global__ __launch_bounds__(1024) void scan6_kernel(const int* __restrict__ cntAll,
                                                     int* __restrict__ rpAll) {
  const int nd[6] = {N_CFG, N_AST, N_CFG, N_AST, N_TEST, N_CFG};
  const int co[6] = {0, 50000, 250000, 300000, 500000, 501000};
  int rrel = blockIdx.x;
  const int* cnt = cntAll + co[rrel];
  int* rp = rpAll + co[rrel] + rrel;
  int n = nd[rrel];
  __shared__ int wsum[16];
  __shared__ int carry;
  int tid = threadIdx.x;
  int lane = tid & 63, wid = tid >> 6;
  if (tid == 0) { carry = 0; rp[0] = 0; }
  __syncthreads();
  for (int base = 0; base < n; base += 4096) {
    int i0 = base + tid * 4;
    int4 v = make_int4(0, 0, 0, 0);
    if (i0 + 3 < n) {
      v = *(const int4*)(cnt + i0);
    } else if (i0 < n) {
      v.x = cnt[i0];
      if (i0 + 1 < n) v.y = cnt[i0 + 1];
      if (i0 + 2 < n) v.z = cnt[i0 + 2];
    }
    int s1 = v.x + v.y, s2 = s1 + v.z, s3 = s2 + v.w;
    int s = s3;
    #pragma unroll
    for (int o = 1; o < 64; o <<= 1) {
      int t = __shfl_up(s, o, 64);
      if (lane >= o) s += t;
    }
    if (lane == 63) wsum[wid] = s;
    __syncthreads();
    if (wid == 0) {
      int x = (lane < 16) ? wsum[lane] : 0;
      #pragma unroll
      for (int o = 1; o < 16; o <<= 1) {
        int t = __shfl_up(x, o, 64);
        if (lane >= o) x += t;
      }
      if (lane < 16) wsum[lane] = x;
    }
    __syncthreads();
    int off = carry + (wid > 0 ? wsum[wid - 1] : 0) + (s - s3);
    if (i0 < n)     rp[i0 + 1] = off + v.x;
    if (i0 + 1 < n) rp[i0 + 2] = off + s1;
    if (i0 + 2 < n) rp[i0 + 3] = off + s2;
    if (i0 + 3 < n) rp[i0 + 4] = off + s3;
    __syncthreads();
    if (tid == 0) carry += wsum[15];
    __syncthreads();
  }
}

__global__ void cursor6_kernel(int* __restrict__ cursorAll, const int* __restrict__ rpAll) {
  int i = blockIdx.x * 256 + threadIdx.x;
  if (i >= ND_TOT) return;
  int r = (i < 50000) ? 0 : (i < 250000) ? 1 : (i < 300000) ? 2
        : (i < 500000) ? 3 : (i < 501000) ? 4 : 5;
  cursorAll[i] = rpAll[i + r];
}

__global__ void scatter6_kernel(const int* __restrict__ s0, const int* __restrict__ s1,
                                const int* __restrict__ s2, const int* __restrict__ s3,
                                const int* __restrict__ s4, const int* __restrict__ s5,
                                const int* __restrict__ d0, const int* __restrict__ d1,
                                const int* __restrict__ d2, const int* __restrict__ d3,
                                const int* __restrict__ d4, const int* __restrict__ d5,
                                int* __restrict__ cursorAll, int* __restrict__ siAll) {
  int i = blockIdx.x * 256 + threadIdx.x;
  if (i >= E_TOT) return;
  int local; int r = rel_of_edge(i, local);
  const int* sp[6] = {s0, s1, s2, s3, s4, s5};
  const int* dp[6] = {d0, d1, d2, d3, d4, d5};
  const int co[6] = {0, 50000, 250000, 300000, 500000, 501000};
  const int eo[6] = {0, 200000, 600000, 800000, 1000000, 1050000};
  int p = atomicAdd(&cursorAll[co[r] + dp[r][local]], 1);
  siAll[eo[r] + p] = sp[r][local];
}

// ---------------------------------------------------------------- encoders (h stored bf16)
__global__ void gather_lbl_kernel(const int* __restrict__ labels, const float* __restrict__ emb,
                                  unsigned short* __restrict__ h, int n) {
  int i = blockIdx.x * 256 + threadIdx.x;
  int node = i >> 5, l = i & 31;
  if (node < n) {
    float4 v = ((const float4*)(emb + (size_t)labels[node] * 128))[l];
    s16x4 o;
    o.x = (short)f2bf(v.x); o.y = (short)f2bf(v.y);
    o.z = (short)f2bf(v.z); o.w = (short)f2bf(v.w);
    *(s16x4*)(h + (size_t)node * 256 + l * 4) = o;
  }
}

__global__ void bcast_temb_kernel(const float* __restrict__ t, unsigned short* __restrict__ h) {
  int i = blockIdx.x * 256 + threadIdx.x;
  int node = i >> 6, l = i & 63;
  if (node < N_TEST) {
    float4 v = ((const float4*)t)[l];
    s16x4 o;
    o.x = (short)f2bf(v.x); o.y = (short)f2bf(v.y);
    o.z = (short)f2bf(v.z); o.w = (short)f2bf(v.w);
    *(s16x4*)(h + (size_t)node * 256 + l * 4) = o;
  }
}

// enc W fp32 [300][128] -> bf16 [128 n][320 k] zero-padded
__global__ void wtenc_kernel(const float* __restrict__ W, unsigned short* __restrict__ Wt) {
  int i = blockIdx.x * 256 + threadIdx.x;
  if (i >= 128 * 320) return;
  int k = i % 320, n = i / 320;
  Wt[i] = (k < 300) ? f2bf(W[(size_t)k * 128 + n]) : (unsigned short)0;
}

// content[M,300] @ W[300,128] + b -> bf16 h[row*256 + 128 + col]
__global__ __launch_bounds__(256) void enc_mfma_kernel(
    const float* __restrict__ A, int M,
    const unsigned short* __restrict__ WtE,   // [128][320] bf16
    const float* __restrict__ bias,           // [128] fp32
    unsigned short* __restrict__ h) {
  __shared__ __align__(16) unsigned short As[2][8192];
  __shared__ __align__(16) unsigned short Bs[2][8192];
  int tid = threadIdx.x, lane = tid & 63, wid = tid >> 6;
  int gm0 = blockIdx.x * 128;

  int wr = wid >> 1, wc = wid & 1;
  f32x4 acc[4][4];
  #pragma unroll
  for (int mi = 0; mi < 4; ++mi)
    #pragma unroll
    for (int ni = 0; ni < 4; ++ni) acc[mi][ni] = (f32x4){0.f, 0.f, 0.f, 0.f};

  auto stageB = [&](int buf, int kt) {
    int k0 = kt * 64;
    #pragma unroll
    for (int j = 0; j < 4; ++j) {
      int q = tid * 4 + j;                 // 0..1023 -> rows 0..127
      int row = q >> 3, sp = q & 7;
      int sgl = sp ^ (row & 7);
      *(uint4*)&Bs[buf][row * 64 + sp * 8] =
          *(const uint4*)(WtE + (size_t)row * 320 + k0 + sgl * 8);
    }
  };
  auto stageA = [&](int buf, int kt) {
    int k0 = kt * 64;
    #pragma unroll
    for (int j = 0; j < 4; ++j) {
      int q = tid * 4 + j;
      int row = q >> 3, s = q & 7;
      int grow = gm0 + row;
      int k = k0 + s * 8;
      float v[8];
      if (grow < M && k + 8 <= 300) {
        float4 u0 = *(const float4*)(A + (size_t)grow * 300 + k);
        float4 u1 = *(const float4*)(A + (size_t)grow * 300 + k + 4);
        v[0] = u0.x; v[1] = u0.y; v[2] = u0.z; v[3] = u0.w;
        v[4] = u1.x; v[5] = u1.y; v[6] = u1.z; v[7] = u1.w;
      } else {
        #pragma unroll
        for (int e = 0; e < 8; ++e)
          v[e] = (grow < M && k + e < 300) ? A[(size_t)grow * 300 + k + e] : 0.f;
      }
      bf16x8 o;
      #pragma unroll
      for (int e = 0; e < 8; ++e) o[e] = (short)f2bf(v[e]);
      *(bf16x8*)&As[buf][row * 64 + ((s ^ (row & 7)) * 8)] = o;
    }
  };

  const int nkt = 5;   // 320 / 64
  stageA(0, 0); stageB(0, 0);
  __syncthreads();
  for (int kt = 0; kt < nkt; ++kt) {
    int cur = kt & 1;
    if (kt + 1 < nkt) { stageA(cur ^ 1, kt + 1); stageB(cur ^ 1, kt + 1); }
    #pragma unroll
    for (int kk = 0; kk < 2; ++kk) {
      bf16x8 af[4], bfr[4];
      int slBase = kk * 4 + (lane >> 4);
      #pragma unroll
      for (int mi = 0; mi < 4; ++mi) {
        int row = wr * 64 + mi * 16 + (lane & 15);
        af[mi] = *(const bf16x8*)&As[cur][row * 64 + ((slBase ^ (row & 7)) * 8)];
      }
      #pragma unroll
      for (int ni = 0; ni < 4; ++ni) {
        int row = wc * 64 + ni * 16 + (lane & 15);
        bfr[ni] = *(const bf16x8*)&Bs[cur][row * 64 + ((slBase ^ (row & 7)) * 8)];
      }
      __builtin_amdgcn_s_setprio(1);
      #pragma unroll
      for (int mi = 0; mi < 4; ++mi)
        #pragma unroll
        for (int ni = 0; ni < 4; ++ni)
          acc[mi][ni] = __builtin_amdgcn_mfma_f32_16x16x32_bf16(bfr[ni], af[mi], acc[mi][ni], 0, 0, 0);
      __builtin_amdgcn_s_setprio(0);
    }
    __syncthreads();
  }

  float4 b4[4];
  #pragma unroll
  for (int ni = 0; ni < 4; ++ni)
    b4[ni] = *(const float4*)(bias + wc * 64 + ni * 16 + (lane >> 4) * 4);
  #pragma unroll
  for (int mi = 0; mi < 4; ++mi) {
    int m = gm0 + wr * 64 + mi * 16 + (lane & 15);
    if (m >= M) continue;
    #pragma unroll
    for (int ni = 0; ni < 4; ++ni) {
      f32x4 v = acc[mi][ni];
      int nb = wc * 64 + ni * 16 + (lane >> 4) * 4;
      s16x4 o;
      o.x = (short)f2bf(v[0] + b4[ni].x);
      o.y = (short)f2bf(v[1] + b4[ni].y);
      o.z = (short)f2bf(v[2] + b4[ni].z);
      o.w = (short)f2bf(v[3] + b4[ni].w);
      *(s16x4*)(h + (size_t)m * 256 + 128 + nb) = o;
    }
  }
}

// ---------------------------------------------------------------- W -> bf16 transpose
__global__ void wt_kernel(const float* __restrict__ W, unsigned short* __restrict__ Wt) {
  int i = blockIdx.x * 256 + threadIdx.x;
  int k = i & 255, n = (i >> 8) & 255, lr = i >> 16;
  Wt[i] = f2bf(W[((size_t)lr * 256 + k) * 256 + n]);
}

// summed bias per (layer, dst-type): bsum[l][dt][256], dt: 0=cfg 1=ast 2=test
__global__ void bsum_kernel(const float* __restrict__ brel, float* __restrict__ bsum) {
  int i = blockIdx.x * 256 + threadIdx.x;
  if (i >= 5 * 3 * 256) return;
  int n = i & 255, dt = (i >> 8) % 3, l = i / (3 * 256);
  float s;
  if (dt == 0)      s = brel[((size_t)l * 6 + 0) * 256 + n] + brel[((size_t)l * 6 + 2) * 256 + n] + brel[((size_t)l * 6 + 5) * 256 + n];
  else if (dt == 1) s = brel[((size_t)l * 6 + 1) * 256 + n] + brel[((size_t)l * 6 + 3) * 256 + n];
  else              s = brel[((size_t)l * 6 + 4) * 256 + n];
  bsum[i] = s;
}

// ---------------------------------------------------------------- merged per-layer aggregation
// HALF-WAVE PER NODE: 32 lanes read one full 512 B h-row per edge (coalesced); no shfl
// reduce, no idle lanes at degree 1. Node slots: [0,200000)=ast, [200000,250000)=cfg,
// [250000,251000)=test. 8 nodes/block. Abuf writes NON-TEMPORAL: A is write-once
// read-once (by GEMM) — bypassing cache keeps the 128 MB h resident in L3
// (round-11: FETCH 280 MB > h's 128 MB = write-stream thrash).
__global__ void agg_all_kernel(
    const unsigned short* __restrict__ hC, const unsigned short* __restrict__ hA,
    const unsigned short* __restrict__ hT,
    const int* __restrict__ rp0, const int* __restrict__ si0,
    const int* __restrict__ rp1, const int* __restrict__ si1,
    const int* __restrict__ rp2, const int* __restrict__ si2,
    const int* __restrict__ rp3, const int* __restrict__ si3,
    const int* __restrict__ rp4, const int* __restrict__ si4,
    const int* __restrict__ rp5, const int* __restrict__ si5,
    unsigned short* __restrict__ Aast, unsigned short* __restrict__ Acfg,
    unsigned short* __restrict__ Atst) {
  int slot = (blockIdx.x * 256 + threadIdx.x) >> 5;
  int l32 = threadIdx.x & 31;
  if (slot >= 251000) return;

  int w, nkt, nrel;
  unsigned short* A;
  const unsigned short* hh[3]; const int* rpp[3]; const int* sii[3];
  if (slot < 200000) {            // ast dst: rels 1 (src ast), 3 (src cfg); K=512
    w = slot; nkt = 8; A = Aast; nrel = 2;
    hh[0] = hA; rpp[0] = rp1; sii[0] = si1;
    hh[1] = hC; rpp[1] = rp3; sii[1] = si3;
    hh[2] = hC; rpp[2] = rp3; sii[2] = si3;
  } else if (slot < 250000) {     // cfg dst: rels 0 (cfg), 2 (ast), 5 (test); K=768
    w = slot - 200000; nkt = 12; A = Acfg; nrel = 3;
    hh[0] = hC; rpp[0] = rp0; sii[0] = si0;
    hh[1] = hA; rpp[1] = rp2; sii[1] = si2;
    hh[2] = hT; rpp[2] = rp5; sii[2] = si5;
  } else {                        // test dst: rel 4 (src cfg); K=256
    w = slot - 250000; nkt = 4; A = Atst; nrel = 1;
    hh[0] = hC; rpp[0] = rp4; sii[0] = si4;
    hh[1] = hC; rpp[1] = rp4; sii[1] = si4;
    hh[2] = hC; rpp[2] = rp4; sii[2] = si4;
  }

  size_t tilebase = ((size_t)(w >> 8) * nkt * 256 + (w & 255)) * 64;   // + kt*16384
  int kt0 = l32 >> 3;            // K-tile within rel segment
  int cc = (l32 & 7) * 8;        // col within tile
  #pragma unroll 1
  for (int rr = 0; rr < nrel; ++rr) {
    const unsigned short* h = hh[rr];
    const int* si = sii[rr];
    int bb = rpp[rr][w], ee = rpp[rr][w + 1];
    float a0 = 0.f, a1 = 0.f, a2 = 0.f, a3 = 0.f,
          a4 = 0.f, a5 = 0.f, a6 = 0.f, a7 = 0.f;
    int i = bb;
    for (; i + 1 < ee; i += 2) {                  // 2 loads in flight
      bf16x8 v0 = *(const bf16x8*)(h + (size_t)si[i] * 256 + l32 * 8);
      bf16x8 v1 = *(const bf16x8*)(h + (size_t)si[i + 1] * 256 + l32 * 8);
      a0 += bf2f((unsigned short)v0[0]); a1 += bf2f((unsigned short)v0[1]);
      a2 += bf2f((unsigned short)v0[2]); a3 += bf2f((unsigned short)v0[3]);
      a4 += bf2f((unsigned short)v0[4]); a5 += bf2f((unsigned short)v0[5]);
      a6 += bf2f((unsigned short)v0[6]); a7 += bf2f((unsigned short)v0[7]);
      a0 += bf2f((unsigned short)v1[0]); a1 += bf2f((unsigned short)v1[1]);
      a2 += bf2f((unsigned short)v1[2]); a3 += bf2f((unsigned short)v1[3]);
      a4 += bf2f((unsigned short)v1[4]); a5 += bf2f((unsigned short)v1[5]);
      a6 += bf2f((unsigned short)v1[6]); a7 += bf2f((unsigned short)v1[7]);
    }
    if (i < ee) {
      bf16x8 v0 = *(const bf16x8*)(h + (size_t)si[i] * 256 + l32 * 8);
      a0 += bf2f((unsigned short)v0[0]); a1 += bf2f((unsigned short)v0[1]);
      a2 += bf2f((unsigned short)v0[2]); a3 += bf2f((unsigned short)v0[3]);
      a4 += bf2f((unsigned short)v0[4]); a5 += bf2f((unsigned short)v0[5]);
      a6 += bf2f((unsigned short)v0[6]); a7 += bf2f((unsigned short)v0[7]);
    }
    u32x4 o;
    o.x = (unsigned int)f2bf(a0) | ((unsigned int)f2bf(a1) << 16);
    o.y = (unsigned int)f2bf(a2) | ((unsigned int)f2bf(a3) << 16);
    o.z = (unsigned int)f2bf(a4) | ((unsigned int)f2bf(a5) << 16);
    o.w = (unsigned int)f2bf(a6) | ((unsigned int)f2bf(a7) << 16);
    __builtin_nontemporal_store(
        o, (u32x4*)(A + tilebase + (size_t)(rr * 4 + kt0) * 16384 + cc));
  }
}

// ---------------------------------------------------------------- merged per-layer MFMA GEMM
// Blocks [0,782)=ast, [782,978)=cfg, [978,982)=test. BM=256, BN=256, 512 thr / 8 waves.
// A K-step-tiled (contiguous 32 KB stage). Double-buffered A+B (128 KB LDS),
// counted-vmcnt(8) pipeline; never vmcnt(0) mid-loop. Round-7 direct epilogue.
__global__ __launch_bounds__(512, 2) void gemm_all_kernel(
    const unsigned short* __restrict__ Aast, const unsigned short* __restrict__ Acfg,
    const unsigned short* __restrict__ Atst,
    const unsigned short* __restrict__ WtL,   // [6][256 n][256 k] bf16, this layer
    const float* __restrict__ bsumL,          // [3][256] summed bias, this layer
    const unsigned short* __restrict__ resA, const unsigned short* __restrict__ resC,
    const unsigned short* __restrict__ resT,
    unsigned short* __restrict__ outA, unsigned short* __restrict__ outC,
    unsigned short* __restrict__ outT) {
  __shared__ __align__(16) unsigned short AsL[2][16384];
  __shared__ __align__(16) unsigned short BsL[2][16384];
  int tid = threadIdx.x, lane = tid & 63, wid = tid >> 6;
  int b = blockIdx.x;

  int mtile, M, nkt, r0, r1, r2, dt;
  const unsigned short* A;
  const unsigned short* residual;
  unsigned short* out;
  if (b < 782) {
    mtile = b;       A = Aast; M = N_AST;  nkt = 8;  r0 = 1; r1 = 3; r2 = 3; dt = 1;
    residual = resA; out = outA;
  } else if (b < 978) {
    mtile = b - 782; A = Acfg; M = N_CFG;  nkt = 12; r0 = 0; r1 = 2; r2 = 5; dt = 0;
    residual = resC; out = outC;
  } else {
    mtile = b - 978; A = Atst; M = N_TEST; nkt = 4;  r0 = 4; r1 = 4; r2 = 4; dt = 2;
    residual = resT; out = outT;
  }
  int gm0 = mtile * 256;
  int rels[3] = {r0, r1, r2};
  const float* bsum = bsumL + dt * 256;

  int wr = wid >> 1, wc = wid & 1;         // 4 (M) x 2 (N) waves
  f32x4 acc[4][8];
  #pragma unroll
  for (int mi = 0; mi < 4; ++mi)
    #pragma unroll
    for (int ni = 0; ni < 8; ++ni) acc[mi][ni] = (f32x4){0.f, 0.f, 0.f, 0.f};

  auto stageA = [&](int buf, int kt) {
    if (kt > nkt - 1) kt = nkt - 1;        // clamp: uniform vmcnt counting at tail
    const unsigned short* base = A + ((size_t)mtile * nkt + kt) * 16384;
    #pragma unroll
    for (int i = 0; i < 4; ++i) {
      int instr = wid * 4 + i;
      int P = instr * 64 + lane;
      int row = P >> 3, sp = P & 7;
      int s = sp ^ (row & 7);
      gload_lds16(base + row * 64 + s * 8, &AsL[buf][instr * 512]);
    }
  };
  auto stageB = [&](int buf, int kt) {
    if (kt > nkt - 1) kt = nkt - 1;
    int k0 = kt * 64;
    #pragma unroll
    for (int i = 0; i < 4; ++i) {
      int instr = wid * 4 + i;
      int P = instr * 64 + lane;
      int row = P >> 3, sp = P & 7;
      int s = sp ^ (row & 7);
      gload_lds16(WtL + ((size_t)rels[k0 >> 8] * 256 + row) * 256 + (k0 & 255) + s * 8,
                  &BsL[buf][instr * 512]);
    }
  };

  // prologue: tiles 0,1 into bufs 0,1 (16 loads/wave); vmcnt(8) forces tile0
  stageA(0, 0); stageB(0, 0); stageA(1, 1); stageB(1, 1);
  asm volatile("s_waitcnt vmcnt(8)" ::: "memory");
  __builtin_amdgcn_s_barrier();

  int cb = 0;
  for (int kt = 0; kt < nkt; ++kt) {
    #pragma unroll
    for (int kk = 0; kk < 2; ++kk) {
      bf16x8 af[4], bfr[8];
      int slBase = kk * 4 + (lane >> 4);
      #pragma unroll
      for (int mi = 0; mi < 4; ++mi) {
        int row = wr * 64 + mi * 16 + (lane & 15);
        af[mi] = *(const bf16x8*)&AsL[cb][row * 64 + ((slBase ^ (row & 7)) * 8)];
      }
      #pragma unroll
      for (int ni = 0; ni < 8; ++ni) {
        int row = wc * 128 + ni * 16 + (lane & 15);
        bfr[ni] = *(const bf16x8*)&BsL[cb][row * 64 + ((slBase ^ (row & 7)) * 8)];
      }
      __builtin_amdgcn_s_setprio(1);
      #pragma unroll
      for (int mi = 0; mi < 4; ++mi)
        #pragma unroll
        for (int ni = 0; ni < 8; ++ni)
          acc[mi][ni] = __builtin_amdgcn_mfma_f32_16x16x32_bf16(bfr[ni], af[mi], acc[mi][ni], 0, 0, 0);
      __builtin_amdgcn_s_setprio(0);
    }
    if (kt + 1 < nkt) {
      __builtin_amdgcn_s_barrier();        // all waves done reading buffer cb
      stageB(cb, kt + 2);                  // overwrite cb with tile kt+2
      stageA(cb, kt + 2);
      asm volatile("s_waitcnt vmcnt(8)" ::: "memory");   // tile kt+1's loads landed
      __builtin_amdgcn_s_barrier();
      cb ^= 1;
    }
  }
  asm volatile("s_waitcnt vmcnt(0)" ::: "memory");       // drain clamped tail loads
  __builtin_amdgcn_sched_barrier(0);

  // epilogue (round-7 form: swapped layout, lane holds 4 consecutive cols of one row)
  float4 b4[8];
  #pragma unroll
  for (int ni = 0; ni < 8; ++ni)
    b4[ni] = *(const float4*)(bsum + wc * 128 + ni * 16 + (lane >> 4) * 4);
  #pragma unroll
  for (int mi = 0; mi < 4; ++mi) {
    int m = gm0 + wr * 64 + mi * 16 + (lane & 15);
    if (m >= M) continue;
    #pragma unroll
    for (int ni = 0; ni < 8; ++ni) {
      f32x4 v = acc[mi][ni];
      int nb = wc * 128 + ni * 16 + (lane >> 4) * 4;
      float x0 = fmaxf(v[0] + b4[ni].x, 0.f);
      float x1 = fmaxf(v[1] + b4[ni].y, 0.f);
      float x2 = fmaxf(v[2] + b4[ni].z, 0.f);
      float x3 = fmaxf(v[3] + b4[ni].w, 0.f);
      if (residual) {
        s16x4 rv = *(const s16x4*)(residual + (size_t)m * 256 + nb);
        x0 += bf2f((unsigned short)rv.x); x1 += bf2f((unsigned short)rv.y);
        x2 += bf2f((unsigned short)rv.z); x3 += bf2f((unsigned short)rv.w);
      }
      s16x4 o;
      o.x = (short)f2bf(x0); o.y = (short)f2bf(x1);
      o.z = (short)f2bf(x2); o.w = (short)f2bf(x3);
      *(s16x4*)(out + (size_t)m * 256 + nb) = o;
    }
  }
}

// ---------------------------------------------------------------- decoders (bf16 h in, fp32 out)
__global__ void decode2_kernel(const unsigned short* __restrict__ h, const float* __restrict__ W,
                               const float* __restrict__ b, float* __restrict__ logits,
                               float* __restrict__ soft, int n) {
  int w = (blockIdx.x * blockDim.x + threadIdx.x) >> 6;
  int lane = threadIdx.x & 63;
  if (w >= n) return;
  s16x4 hv = *(const s16x4*)(h + (size_t)w * 256 + lane * 4);
  float x0 = bf2f((unsigned short)hv.x), x1 = bf2f((unsigned short)hv.y);
  float x2 = bf2f((unsigned short)hv.z), x3 = bf2f((unsigned short)hv.w);
  int k = lane * 4;
  float l0 = x0 * W[(k + 0) * 2 + 0] + x1 * W[(k + 1) * 2 + 0] +
             x2 * W[(k + 2) * 2 + 0] + x3 * W[(k + 3) * 2 + 0];
  float l1 = x0 * W[(k + 0) * 2 + 1] + x1 * W[(k + 1) * 2 + 1] +
             x2 * W[(k + 2) * 2 + 1] + x3 * W[(k + 3) * 2 + 1];
  #pragma unroll
  for (int m = 1; m < 64; m <<= 1) {
    l0 += __shfl_xor(l0, m, 64);
    l1 += __shfl_xor(l1, m, 64);
  }
  if (lane == 0) {
    l0 += b[0]; l1 += b[1];
    float mx = fmaxf(l0, l1);
    float e0 = expf(l0 - mx), e1 = expf(l1 - mx);
    float s = e0 + e1;
    logits[(size_t)w * 2 + 0] = l0;
    logits[(size_t)w * 2 + 1] = l1;
    soft[(size_t)w * 2 + 0] = e0 / s;
    soft[(size_t)w * 2 + 1] = e1 / s;
  }
}

__global__ void decode3_kernel(const unsigned short* __restrict__ h, const float* __restrict__ W,
                               const float* __restrict__ b, float* __restrict__ logits,
                               float* __restrict__ soft, int n) {
  int w = (blockIdx.x * blockDim.x + threadIdx.x) >> 6;
  int lane = threadIdx.x & 63;
  if (w >= n) return;
  s16x4 hv = *(const s16x4*)(h + (size_t)w * 256 + lane * 4);
  float x0 = bf2f((unsigned short)hv.x), x1 = bf2f((unsigned short)hv.y);
  float x2 = bf2f((unsigned short)hv.z), x3 = bf2f((unsigned short)hv.w);
  int k = lane * 4;
  float l0 = x0 * W[(k + 0) * 3 + 0] + x1 * W[(k + 1) * 3 + 0] +
             x2 * W[(k + 2) * 3 + 0] + x3 * W[(k + 3) * 3 + 0];
  float l1 = x0 * W[(k + 0) * 3 + 1] + x1 * W[(k + 1) * 3 + 1] +
             x2 * W[(k + 2) * 3 + 1] + x3 * W[(k + 3) * 3 + 1];
  float l2 = x0 * W[(k + 0) * 3 + 2] + x1 * W[(k + 1) * 3 + 2] +
             x2 * W[(k + 2) * 3 + 2] + x3 * W[(k + 3) * 3 + 2];
  #pragma unroll
  for (int m = 1; m < 64; m <<= 1) {
    l0 += __shfl_xor(l0, m, 64);
    l1 += __shfl_xor(l1, m, 64);
    l2 += __shfl_xor(l2, m, 64);
  }
  if (lane == 0) {
    l0 += b[0]; l1 += b[1]; l2 += b[2];
    float mx = fmaxf(fmaxf(l0, l1), l2);
    float e0 = expf(l0 - mx), e1 = expf(l1 - mx), e2 = expf(l2 - mx);
    float s = e0 + e1 + e2;
    logits[(size_t)w * 3 + 0] = l0;
    logits[(size_t)w * 3 + 1] = l1;
    logits[(size_t)w * 3 + 2] = l2;
    soft[(size_t)w * 3 + 0] = e0 / s;
    soft[(size_t)w * 3 + 1] = e1 / s;
    soft[(size_t)w * 3 + 2] = e2 / s;
  }
}

// ---------------------------------------------------------------- host
extern "C" void kernel_launch(void* const* d_in, const int* in_sizes, int n_in,
                              void* d_out, int out_size, void* d_ws, size_t ws_size,
                              hipStream_t stream) {
  (void)in_sizes; (void)n_in; (void)out_size; (void)ws_size;
  const int*   c_labels  = (const int*)  d_in[0];
  const float* c_content = (const float*)d_in[1];
  const int*   a_labels  = (const int*)  d_in[2];
  const float* a_content = (const float*)d_in[3];
  const int*   edges[6];
  for (int r = 0; r < 6; ++r) edges[r] = (const int*)d_in[4 + r];
  const float* c_lbl_emb = (const float*)d_in[10];
  const float* c_enc_W   = (const float*)d_in[11];
  const float* c_enc_b   = (const float*)d_in[12];
  const float* a_lbl_emb = (const float*)d_in[13];
  const float* a_enc_W   = (const float*)d_in[14];
  const float* a_enc_b   = (const float*)d_in[15];
  const float* t_emb     = (const float*)d_in[16];
  const float* W_rel     = (const float*)d_in[17];
  const float* b_rel     = (const float*)d_in[18];
  const float* dec_W     = (const float*)d_in[19];
  const float* dec_b     = (const float*)d_in[20];
  const float* adec_W    = (const float*)d_in[21];
  const float* adec_b    = (const float*)d_in[22];
  float* out = (float*)d_out;

  static const int E_CNT[6] = {200000, 400000, 200000, 200000, 50000, 50000};
  static const int RO[6]    = {0, 50001, 250002, 300003, 500004, 501005};  // rp offsets
  static const int SO[6]    = {0, 200000, 600000, 800000, 1000000, 1050000};

  char* ws = (char*)d_ws;
  size_t off = 0;
  auto alloc = [&](size_t bytes) -> void* {
    void* p = ws + off;
    off += (bytes + 255) & ~(size_t)255;
    return p;
  };
  unsigned short* buf0 = (unsigned short*)alloc((size_t)NNODE * 256 * 2);
  unsigned short* buf1 = (unsigned short*)alloc((size_t)NNODE * 256 * 2);
  unsigned short* Aast = (unsigned short*)alloc((size_t)782 * 8 * 16384 * 2);
  unsigned short* Acfg = (unsigned short*)alloc((size_t)196 * 12 * 16384 * 2);
  unsigned short* Atst = (unsigned short*)alloc((size_t)4 * 4 * 16384 * 2);
  unsigned short* Wt   = (unsigned short*)alloc((size_t)5 * 6 * 256 * 256 * 2);
  unsigned short* WtEc = (unsigned short*)alloc((size_t)128 * 320 * 2);
  unsigned short* WtEa = (unsigned short*)alloc((size_t)128 * 320 * 2);
  float*          bsum = (float*)alloc((size_t)5 * 3 * 256 * 4);
  int* cntAll = (int*)alloc((size_t)ND_TOT * 4);          // also reused as cursor
  int* rpAll  = (int*)alloc((size_t)(ND_TOT + 6) * 4);
  int* siAll  = (int*)alloc((size_t)E_TOT * 4);

  // weights -> bf16; bias sums
  wt_kernel<<<CDIV(5 * 6 * 256 * 256, 256), 256, 0, stream>>>(W_rel, Wt);
  wtenc_kernel<<<CDIV(128 * 320, 256), 256, 0, stream>>>(c_enc_W, WtEc);
  wtenc_kernel<<<CDIV(128 * 320, 256), 256, 0, stream>>>(a_enc_W, WtEa);
  bsum_kernel<<<CDIV(5 * 3 * 256, 256), 256, 0, stream>>>(b_rel, bsum);

  // merged CSR build (5 launches; 6 scans run as 6 concurrent blocks)
  const int* d0 = edges[0] + E_CNT[0]; const int* d1 = edges[1] + E_CNT[1];
  const int* d2 = edges[2] + E_CNT[2]; const int* d3 = edges[3] + E_CNT[3];
  const int* d4 = edges[4] + E_CNT[4]; const int* d5 = edges[5] + E_CNT[5];
  zero_int_kernel<<<CDIV(ND_TOT, 256), 256, 0, stream>>>(cntAll, ND_TOT);
  hist6_kernel<<<CDIV(E_TOT, 256), 256, 0, stream>>>(d0, d1, d2, d3, d4, d5, cntAll);
  scan6_kernel<<<6, 1024, 0, stream>>>(cntAll, rpAll);
  cursor6_kernel<<<CDIV(ND_TOT, 256), 256, 0, stream>>>(cntAll, rpAll);
  scatter6_kernel<<<CDIV(E_TOT, 256), 256, 0, stream>>>(
      edges[0], edges[1], edges[2], edges[3], edges[4], edges[5],
      d0, d1, d2, d3, d4, d5, cntAll, siAll);

  const size_t OFF_CFG = 0;
  const size_t OFF_AST = (size_t)N_CFG * 256;
  const size_t OFF_TST = (size_t)(N_CFG + N_AST) * 256;

  // encoders -> buf0 (bf16)
  gather_lbl_kernel<<<CDIV(N_CFG * 32, 256), 256, 0, stream>>>(c_labels, c_lbl_emb, buf0 + OFF_CFG, N_CFG);
  gather_lbl_kernel<<<CDIV(N_AST * 32, 256), 256, 0, stream>>>(a_labels, a_lbl_emb, buf0 + OFF_AST, N_AST);
  enc_mfma_kernel<<<CDIV(N_CFG, 128), 256, 0, stream>>>(c_content, N_CFG, WtEc, c_enc_b, buf0 + OFF_CFG);
  enc_mfma_kernel<<<CDIV(N_AST, 128), 256, 0, stream>>>(a_content, N_AST, WtEa, a_enc_b, buf0 + OFF_AST);
  bcast_temb_kernel<<<CDIV(N_TEST * 64, 256), 256, 0, stream>>>(t_emb, buf0 + OFF_TST);

  unsigned short* h_in = buf0;
  unsigned short* h_out = buf1;
  for (int l = 0; l < 5; ++l) {
    bool use_res = (l == 1 || l == 3);
    const unsigned short* WtL = Wt + (size_t)l * 6 * 256 * 256;
    const float* bsumL = bsum + (size_t)l * 3 * 256;
    agg_all_kernel<<<31375, 256, 0, stream>>>(
        h_in + OFF_CFG, h_in + OFF_AST, h_in + OFF_TST,
        rpAll + RO[0], siAll + SO[0], rpAll + RO[1], siAll + SO[1],
        rpAll + RO[2], siAll + SO[2], rpAll + RO[3], siAll + SO[3],
        rpAll + RO[4], siAll + SO[4], rpAll + RO[5], siAll + SO[5],
        Aast, Acfg, Atst);
    gemm_all_kernel<<<982, 512, 0, stream>>>(
        Aast, Acfg, Atst, WtL, bsumL,
        use_res ? h_in + OFF_AST : nullptr,
        use_res ? h_in + OFF_CFG : nullptr,
        use_res ? h_in + OFF_TST : nullptr,
        h_out + OFF_AST, h_out + OFF_CFG, h_out + OFF_TST);
    unsigned short* t = h_in; h_in = h_out; h_out = t;
  }

  decode2_kernel<<<CDIV(N_CFG, 4), 256, 0, stream>>>(h_in + OFF_CFG, dec_W, dec_b,
                                                     out, out + 100000, N_CFG);
  decode3_kernel<<<CDIV(N_AST, 4), 256, 0, stream>>>(h_in + OFF_AST, adec_W, adec_b,
                                                     out + 200000, out + 800000, N_AST);
}